// Round 4
// baseline (449.564 us; speedup 1.0000x reference)
//
#include <hip/hip_runtime.h>
#include <hip/hip_bf16.h>
#include <cstdint>

typedef __bf16 bf16;
typedef __attribute__((ext_vector_type(8))) __bf16 bf16x8;
typedef __attribute__((ext_vector_type(4))) __bf16 bf16x4;
typedef __attribute__((ext_vector_type(2))) __bf16 bf16x2;
typedef __attribute__((ext_vector_type(4))) float f32x4;

#define N_NODES    65536
#define NUM_GRAPHS 512
#define MAX_N      192
#define D          512
#define H          8
#define DH         64
#define UMAX       64
#define USTRIDE    132

__device__ __forceinline__ void gload_lds16(const void* g, void* l) {
    __builtin_amdgcn_global_load_lds((const __attribute__((address_space(1))) void*)g,
                                     (__attribute__((address_space(3))) void*)l, 16, 0, 0);
}

// ---------------- kernel: graph boundaries ----------------
__global__ __launch_bounds__(256) void lb_kernel(const int* __restrict__ batch,
                                                 int* __restrict__ lb) {
    int g = blockIdx.x * 256 + threadIdx.x;
    if (g > NUM_GRAPHS) return;
    int lo = 0, hi = N_NODES;
    while (lo < hi) {
        int mid = (lo + hi) >> 1;
        if (batch[mid] < g) lo = mid + 1; else hi = mid;
    }
    lb[g] = lo;
}

// ---------------- kernel: per-graph unique Q-row patterns ----------------
// serial pass runs entirely in LDS (was: ~192 dependent global RMWs).
__global__ __launch_bounds__(192) void dedup_kernel(const int* __restrict__ lb,
                                                    int* __restrict__ udata) {
    const int g = blockIdx.x;
    const int off = lb[g];
    const int n = min(lb[g + 1] - off, MAX_N);
    __shared__ int keys[MAX_N];
    __shared__ int ukey[UMAX], ucnt[UMAX];
    __shared__ int nu_s;
    const int t = threadIdx.x;
    if (t < n) {
        unsigned un = (unsigned)n;
        int key = 0;
        #pragma unroll
        for (int p = 0; p < 8; p++) key |= (int)(((unsigned)(8 * t + p)) / un) << (3 * p);
        keys[t] = key;
    }
    __syncthreads();
    if (t == 0) {
        int nu = 0;
        for (int s = 0; s < n; s++) {
            if (s == 0 || keys[s] != keys[s - 1]) {
                if (nu < UMAX) { ukey[nu] = keys[s]; ucnt[nu] = 0; nu++; }
            }
            ucnt[nu - 1] += 1;
        }
        nu_s = nu;
    }
    __syncthreads();
    const int nu = nu_s;
    int* base = udata + (size_t)g * USTRIDE;
    if (t == 0) base[0] = nu;
    if (t < nu) { base[1 + t] = ukey[t]; base[65 + t] = ucnt[t]; }
}

// ---------------- kernel: fp32 -> bf16 convert ----------------
__global__ __launch_bounds__(256) void cvt_kernel(const float* __restrict__ src,
                                                  bf16* __restrict__ dst, int n) {
    int i = (blockIdx.x * 256 + threadIdx.x) * 4;
    if (i >= n) return;
    float4 v = *(const float4*)(src + i);
    bf16x4 o = {(bf16)v.x, (bf16)v.y, (bf16)v.z, (bf16)v.w};
    *(bf16x4*)(dst + i) = o;
}

// ---------------- kernel: P2[h][p][o] = sum_j gq[h*64+j]*wq[o,64p+j] ----------------
__global__ __launch_bounds__(256) void p2_kernel(const float* __restrict__ gq,
                                                 const float* __restrict__ wq,
                                                 float* __restrict__ P2) {
    int h = blockIdx.x, p = blockIdx.y;
    __shared__ float gs[64];
    if (threadIdx.x < 64) gs[threadIdx.x] = gq[h * 64 + threadIdx.x];
    __syncthreads();
    for (int o = threadIdx.x; o < D; o += 256) {
        const float* wr = wq + (size_t)o * D + p * 64;
        float acc = 0.f;
        #pragma unroll 16
        for (int j = 0; j < 64; j++) acc += gs[j] * wr[j];
        P2[(size_t)(h * 8 + p) * D + o] = acc;
    }
}

// ---------------- kernel: Wov[o, h*512+d'] = sum_j wo[o,h*64+j]*wv[h*64+j,d'] ----------------
__global__ __launch_bounds__(256) void wov_kernel(const float* __restrict__ wo,
                                                  const float* __restrict__ wv,
                                                  bf16* __restrict__ Wov) {
    const int ot = blockIdx.x;   // o block of 32
    const int h  = blockIdx.y;
    __shared__ float wos[32 * 64];
    for (int idx = threadIdx.x; idx < 32 * 64; idx += 256) {
        int ol = idx >> 6, j = idx & 63;
        wos[idx] = wo[(size_t)(ot * 32 + ol) * D + h * 64 + j];
    }
    __syncthreads();
    const int c = threadIdx.x * 2;
    float acc0[32] = {}, acc1[32] = {};
    for (int j = 0; j < 64; j++) {
        float2 v2 = *(const float2*)(wv + (size_t)(h * 64 + j) * D + c);
        #pragma unroll
        for (int o = 0; o < 32; o++) {
            float wj = wos[o * 64 + j];
            acc0[o] += wj * v2.x; acc1[o] += wj * v2.y;
        }
    }
    #pragma unroll
    for (int o = 0; o < 32; o++) {
        bf16x2 r = {(bf16)acc0[o], (bf16)acc1[o]};
        *(bf16x2*)(Wov + (size_t)(ot * 32 + o) * 4096 + h * 512 + c) = r;
    }
}

// ---------------- kernel: cst[o] = wo[o,:].bv + bo[o] ----------------
__global__ __launch_bounds__(256) void cst_kernel(const float* __restrict__ wo,
                                                  const float* __restrict__ bv,
                                                  const float* __restrict__ bo,
                                                  float* __restrict__ cst) {
    int o = blockIdx.x * 256 + threadIdx.x;
    if (o >= D) return;
    const float* wr = wo + (size_t)o * D;
    float acc = bo[o];
    for (int d0 = 0; d0 < D; d0 += 4) {
        float4 wv4 = *(const float4*)(wr + d0);
        float4 b4  = *(const float4*)(bv + d0);
        acc += wv4.x * b4.x + wv4.y * b4.y + wv4.z * b4.z + wv4.w * b4.w;
    }
    cst[o] = acc;
}

// ---------------- kernel: K GEMM, 128x128 tile ----------------
// round-0 structure (global_load_lds both operands, linear [128][32] LDS --
// measured fastest; reg-staging both operands was +40% slower, m151-consistent)
// + XCD-swizzled grid (A slab L2-resident across its 4 n-tile users)
// + LDS-staged epilogue (coalesced 16B stores, no RMW write inflation).
__global__ __launch_bounds__(256) void k_gemm(const bf16* __restrict__ Ab,
                                              const bf16* __restrict__ Wkb,
                                              const float* __restrict__ bkb,
                                              bf16* __restrict__ Kout) {
    const int lin = blockIdx.x;          // 0..2047
    const int xcd = lin & 7;
    const int idx = lin >> 3;            // 0..255
    const int nt  = idx & 3;             // n-tile fast within XCD
    const int ml  = idx >> 2;            // 0..63
    const int i0 = (xcd * 64 + ml) * 128;
    const int o0 = nt * 128;

    __shared__ char smem[16896];         // As[128][32]@0 | Bs[128][32]@8192; Cs[64][132] overlays
    bf16* As = (bf16*)smem;
    bf16* Bs = (bf16*)(smem + 8192);
    const int tid = threadIdx.x;
    const int lane = tid & 63;
    const int w = tid >> 6;
    const int wm = w & 1, wn = w >> 1;
    const int fr = lane & 15, quad = lane >> 4;
    const bf16* gA = Ab + (size_t)(i0 + w * 32 + (lane >> 2)) * D + (lane & 3) * 8;
    const bf16* gB = Wkb + (size_t)(o0 + w * 32 + (lane >> 2)) * D + (lane & 3) * 8;
    bf16* lA = As + (w * 32) * 32;
    bf16* lB = Bs + (w * 32) * 32;

    f32x4 acc[4][4] = {};

    for (int kt = 0; kt < D; kt += 32) {
        __syncthreads();
        gload_lds16(gA + kt, lA);
        gload_lds16(gA + (size_t)16 * D + kt, lA + 16 * 32);
        gload_lds16(gB + kt, lB);
        gload_lds16(gB + (size_t)16 * D + kt, lB + 16 * 32);
        __syncthreads();
        bf16x8 fa[4], fb[4];
        #pragma unroll
        for (int mf = 0; mf < 4; mf++)
            fa[mf] = *(const bf16x8*)(As + (wm * 64 + mf * 16 + fr) * 32 + quad * 8);
        #pragma unroll
        for (int nf = 0; nf < 4; nf++)
            fb[nf] = *(const bf16x8*)(Bs + (wn * 64 + nf * 16 + fr) * 32 + quad * 8);
        #pragma unroll
        for (int mf = 0; mf < 4; mf++)
            #pragma unroll
            for (int nf = 0; nf < 4; nf++)
                acc[mf][nf] = __builtin_amdgcn_mfma_f32_16x16x32_bf16(fa[mf], fb[nf], acc[mf][nf], 0, 0, 0);
    }

    // epilogue: stage each 64-row half in LDS (stride 132 -> conflict-free),
    // then coalesced bf16x8 stores.
    bf16* Cs = (bf16*)smem;
    #pragma unroll
    for (int pass = 0; pass < 2; pass++) {
        __syncthreads();
        if (wm == pass) {
            #pragma unroll
            for (int nf = 0; nf < 4; nf++) {
                const int col = wn * 64 + nf * 16 + fr;
                const float bs = bkb[o0 + col];
                #pragma unroll
                for (int mf = 0; mf < 4; mf++) {
                    #pragma unroll
                    for (int r = 0; r < 4; r++)
                        Cs[(mf * 16 + quad * 4 + r) * 132 + col] = (bf16)(acc[mf][nf][r] + bs);
                }
            }
        }
        __syncthreads();
        #pragma unroll
        for (int k = 0; k < 4; k++) {
            int idx2 = k * 256 + tid;            // 0..1023
            int row = idx2 >> 4;                 // 0..63
            int coff = (idx2 & 15) * 8;          // 0..120
            bf16x8 v = *(const bf16x8*)(Cs + row * 132 + coff);
            *(bf16x8*)(Kout + (size_t)(i0 + pass * 64 + row) * D + o0 + coff) = v;
        }
    }
}

// ---------------- kernel: attention + fused abar ----------------
// grid NUM_GRAPHS blocks x 512 threads; wave w == head h.  K fragments for
// this (g,h) are hoisted into REGISTERS once (24 x bf16x8) -- previously the
// c0 loop (typ. 4 iters, nu~50-64) re-read all of K from L3 every iteration.
// abar phase: thread tid owns output column tid for all 8 heads.
__global__ __launch_bounds__(512) void attn_kernel(const bf16* __restrict__ Kb,
                                                   const float* __restrict__ P2,
                                                   const float* __restrict__ bq,
                                                   const int* __restrict__ lb,
                                                   const int* __restrict__ udata,
                                                   const float* __restrict__ Af,
                                                   bf16* __restrict__ abar) {
    const int g = blockIdx.x;
    const int tid = threadIdx.x;
    const int lane = tid & 63;
    const int w = tid >> 6;          // 0..7 == head
    const int h = w;
    const int off = lb[g];
    const int n = min(lb[g + 1] - off, MAX_N);

    __shared__ bf16 Qs[8][16 * 80];
    __shared__ float wacc[8][MAX_N];
    __shared__ int upat_l[UMAX], ucnt_l[UMAX];

    bf16* outg = abar + (size_t)g * 4096;
    if (n == 0) {
        const bf16 z0 = (bf16)0.f;
        bf16x8 z = {z0, z0, z0, z0, z0, z0, z0, z0};
        *(bf16x8*)(outg + tid * 8) = z;
        return;
    }

    const int* ubase = udata + (size_t)g * USTRIDE;
    const int nu = ubase[0];
    if (tid < 64) {
        upat_l[tid] = (tid < nu) ? ubase[1 + tid] : 0;
        ucnt_l[tid] = (tid < nu) ? ubase[65 + tid] : 0;
    }
    wacc[w][lane] = 0.f; wacc[w][64 + lane] = 0.f; wacc[w][128 + lane] = 0.f;
    __syncthreads();

    const int fr = lane & 15;
    const int quad = lane >> 4;
    const float inv_n = 1.0f / (float)n;

    // hoist K into registers: lane holds K rows (st*16+fr) cols h*64+quad*8..
    bf16x8 kf0[12], kf1[12];
    #pragma unroll
    for (int st = 0; st < 12; st++) {
        int s = st * 16 + fr;
        int row = off + (s < n ? s : n - 1);       // clamped: always valid
        const bf16* kp = Kb + (size_t)row * D + h * 64 + quad * 8;
        kf0[st] = *(const bf16x8*)kp;
        kf1[st] = *(const bf16x8*)(kp + 32);
    }

    for (int c0 = 0; c0 < nu; c0 += 16) {
        {   // build 16 Q rows (bf16) in wave-private LDS
            const int ul = lane >> 2;
            const int j0 = (lane & 3) * 16;
            const bool valid = (c0 + ul) < nu;
            const int pat = upat_l[c0 + ul];
            const float* bpq = bq + h * 64 + j0;
            float4 q0 = *(const float4*)bpq;
            float4 q1 = *(const float4*)(bpq + 4);
            float4 q2 = *(const float4*)(bpq + 8);
            float4 q3 = *(const float4*)(bpq + 12);
            #pragma unroll
            for (int p = 0; p < 8; p++) {
                const int hp = (pat >> (3 * p)) & 7;
                const float* pp = P2 + (size_t)(hp * 8 + p) * D + h * 64 + j0;
                float4 t0 = *(const float4*)pp;
                float4 t1 = *(const float4*)(pp + 4);
                float4 t2 = *(const float4*)(pp + 8);
                float4 t3 = *(const float4*)(pp + 12);
                q0.x += t0.x; q0.y += t0.y; q0.z += t0.z; q0.w += t0.w;
                q1.x += t1.x; q1.y += t1.y; q1.z += t1.z; q1.w += t1.w;
                q2.x += t2.x; q2.y += t2.y; q2.z += t2.z; q2.w += t2.w;
                q3.x += t3.x; q3.y += t3.y; q3.z += t3.z; q3.w += t3.w;
            }
            if (!valid) {
                q0.x=q0.y=q0.z=q0.w=0.f; q1.x=q1.y=q1.z=q1.w=0.f;
                q2.x=q2.y=q2.z=q2.w=0.f; q3.x=q3.y=q3.z=q3.w=0.f;
            }
            bf16x8 b0 = {(bf16)q0.x,(bf16)q0.y,(bf16)q0.z,(bf16)q0.w,
                         (bf16)q1.x,(bf16)q1.y,(bf16)q1.z,(bf16)q1.w};
            bf16x8 b1 = {(bf16)q2.x,(bf16)q2.y,(bf16)q2.z,(bf16)q2.w,
                         (bf16)q3.x,(bf16)q3.y,(bf16)q3.z,(bf16)q3.w};
            *(bf16x8*)(&Qs[w][ul * 80 + j0])     = b0;
            *(bf16x8*)(&Qs[w][ul * 80 + j0 + 8]) = b1;
        }
        bf16x8 fa0 = *(const bf16x8*)(&Qs[w][fr * 80 + quad * 8]);
        bf16x8 fa1 = *(const bf16x8*)(&Qs[w][fr * 80 + 32 + quad * 8]);

        f32x4 sc[12];
        #pragma unroll
        for (int st = 0; st < 12; st++) {
            if (st * 16 < n) {
                int s = st * 16 + fr;
                f32x4 a = {0.f, 0.f, 0.f, 0.f};
                a = __builtin_amdgcn_mfma_f32_16x16x32_bf16(fa0, kf0[st], a, 0, 0, 0);
                a = __builtin_amdgcn_mfma_f32_16x16x32_bf16(fa1, kf1[st], a, 0, 0, 0);
                if (s < n) {
                    sc[st].x = a.x * 0.125f; sc[st].y = a.y * 0.125f;
                    sc[st].z = a.z * 0.125f; sc[st].w = a.w * 0.125f;
                } else {
                    sc[st].x = sc[st].y = sc[st].z = sc[st].w = -1e30f;
                }
            } else {
                sc[st].x = sc[st].y = sc[st].z = sc[st].w = -1e30f;
            }
        }
        float m[4] = {-1e30f, -1e30f, -1e30f, -1e30f};
        #pragma unroll
        for (int st = 0; st < 12; st++) {
            m[0] = fmaxf(m[0], sc[st].x); m[1] = fmaxf(m[1], sc[st].y);
            m[2] = fmaxf(m[2], sc[st].z); m[3] = fmaxf(m[3], sc[st].w);
        }
        #pragma unroll
        for (int o = 1; o <= 8; o <<= 1) {
            #pragma unroll
            for (int r = 0; r < 4; r++) m[r] = fmaxf(m[r], __shfl_xor(m[r], o));
        }
        float den[4] = {0.f, 0.f, 0.f, 0.f};
        #pragma unroll
        for (int st = 0; st < 12; st++) {
            float e0 = __expf(sc[st].x - m[0]); float e1 = __expf(sc[st].y - m[1]);
            float e2 = __expf(sc[st].z - m[2]); float e3 = __expf(sc[st].w - m[3]);
            sc[st].x = e0; sc[st].y = e1; sc[st].z = e2; sc[st].w = e3;
            den[0] += e0; den[1] += e1; den[2] += e2; den[3] += e3;
        }
        #pragma unroll
        for (int o = 1; o <= 8; o <<= 1) {
            #pragma unroll
            for (int r = 0; r < 4; r++) den[r] += __shfl_xor(den[r], o);
        }
        float wf[4];
        #pragma unroll
        for (int r = 0; r < 4; r++)
            wf[r] = (float)ucnt_l[c0 + quad * 4 + r] * inv_n / den[r];
        #pragma unroll
        for (int st = 0; st < 12; st++) {
            float v = sc[st].x * wf[0] + sc[st].y * wf[1] + sc[st].z * wf[2] + sc[st].w * wf[3];
            v += __shfl_xor(v, 16);
            v += __shfl_xor(v, 32);
            if (lane < 16) wacc[w][st * 16 + lane] += v;
        }
    }

    // ---- fused abar: thread tid owns column tid for all 8 heads ----
    __syncthreads();
    const float* Ac = Af + (size_t)off * D + tid;
    float accv[8] = {};
    for (int s = 0; s < n; s++) {
        float av = Ac[(size_t)s * D];
        #pragma unroll
        for (int hh = 0; hh < 8; hh++) accv[hh] += wacc[hh][s] * av;
    }
    #pragma unroll
    for (int hh = 0; hh < 8; hh++) outg[hh * 512 + tid] = (bf16)accv[hh];
}

// ---------------- kernel: zero tmp ----------------
__global__ __launch_bounds__(256) void zero_kernel(float* __restrict__ p, int n4) {
    int i = blockIdx.x * 256 + threadIdx.x;
    if (i < n4) { float4 z = {0.f, 0.f, 0.f, 0.f}; *(float4*)(p + i * 4) = z; }
}

// ---------------- kernel: fused Wov GEMM, M=512 N=512 K=4096, split-K atomics ----------------
__global__ __launch_bounds__(256) void og_gemm(const bf16* __restrict__ Ab,
                                               const bf16* __restrict__ Bb,
                                               float* __restrict__ Yt) {
    const int o0 = blockIdx.x * 128;
    const int i0 = blockIdx.y * 128;
    const int k0 = blockIdx.z * 512;
    __shared__ bf16 As[128 * 32];
    __shared__ bf16 Bs[128 * 32];
    const int tid = threadIdx.x;
    const int lane = tid & 63;
    const int w = tid >> 6;
    const int wm = w & 1, wn = w >> 1;
    const int fr = lane & 15, quad = lane >> 4;
    const bf16* gA = Ab + (size_t)(i0 + w * 32 + (lane >> 2)) * 4096 + k0 + (lane & 3) * 8;
    const bf16* gB = Bb + (size_t)(o0 + w * 32 + (lane >> 2)) * 4096 + k0 + (lane & 3) * 8;
    bf16* lA = As + (w * 32) * 32;
    bf16* lB = Bs + (w * 32) * 32;

    f32x4 acc[4][4] = {};

    for (int kt = 0; kt < 512; kt += 32) {
        __syncthreads();
        gload_lds16(gA + kt, lA);
        gload_lds16(gA + (size_t)16 * 4096 + kt, lA + 16 * 32);
        gload_lds16(gB + kt, lB);
        gload_lds16(gB + (size_t)16 * 4096 + kt, lB + 16 * 32);
        __syncthreads();
        bf16x8 fa[4], fb[4];
        #pragma unroll
        for (int mf = 0; mf < 4; mf++)
            fa[mf] = *(const bf16x8*)(As + (wm * 64 + mf * 16 + fr) * 32 + quad * 8);
        #pragma unroll
        for (int nf = 0; nf < 4; nf++)
            fb[nf] = *(const bf16x8*)(Bs + (wn * 64 + nf * 16 + fr) * 32 + quad * 8);
        #pragma unroll
        for (int mf = 0; mf < 4; mf++)
            #pragma unroll
            for (int nf = 0; nf < 4; nf++)
                acc[mf][nf] = __builtin_amdgcn_mfma_f32_16x16x32_bf16(fa[mf], fb[nf], acc[mf][nf], 0, 0, 0);
    }
    #pragma unroll
    for (int nf = 0; nf < 4; nf++) {
        const int col = o0 + wn * 64 + nf * 16 + fr;
        #pragma unroll
        for (int mf = 0; mf < 4; mf++) {
            const int row = i0 + wm * 64 + mf * 16 + quad * 4;
            #pragma unroll
            for (int r = 0; r < 4; r++)
                atomicAdd(&Yt[(size_t)(row + r) * D + col], acc[mf][nf][r]);
        }
    }
}

// ---------------- kernel: final projection out = relu((tmp+cst|0) @ Wp^T + bp) ----------------
__global__ __launch_bounds__(256) void proj_p(const float* __restrict__ tmp,
                                              const float* __restrict__ cst,
                                              const bf16* __restrict__ Wpb,
                                              const float* __restrict__ bp,
                                              const int* __restrict__ lb,
                                              float* __restrict__ out) {
    const int o0 = blockIdx.x * 128;
    const int i0 = blockIdx.y * 128;
    __shared__ bf16 As[128 * 32];
    __shared__ bf16 Bs[128 * 32];
    const int tid = threadIdx.x;
    const int lane = tid & 63;
    const int w = tid >> 6;
    const int wm = w & 1, wn = w >> 1;
    const int fr = lane & 15, quad = lane >> 4;
    const int ar = tid >> 1;
    const int ac = (tid & 1) * 16;
    const int g = i0 + ar;
    const bool live = lb[g + 1] - lb[g] > 0;
    const float* tp = tmp + (size_t)g * D + ac;
    const float* cp = cst + ac;
    const bf16* gB = Wpb + (size_t)(o0 + w * 32 + (lane >> 2)) * D + (lane & 3) * 8;
    bf16* lB = Bs + (w * 32) * 32;

    f32x4 acc[4][4] = {};

    for (int kt = 0; kt < D; kt += 32) {
        __syncthreads();
        gload_lds16(gB + kt, lB);
        gload_lds16(gB + (size_t)16 * D + kt, lB + 16 * 32);
        {
            float4 x0 = *(const float4*)(tp + kt);
            float4 x1 = *(const float4*)(tp + kt + 4);
            float4 x2 = *(const float4*)(tp + kt + 8);
            float4 x3 = *(const float4*)(tp + kt + 12);
            float4 c0 = *(const float4*)(cp + kt);
            float4 c1 = *(const float4*)(cp + kt + 4);
            float4 c2 = *(const float4*)(cp + kt + 8);
            float4 c3 = *(const float4*)(cp + kt + 12);
            float s = live ? 1.f : 0.f;
            bf16x8 v0 = {(bf16)((x0.x+c0.x)*s),(bf16)((x0.y+c0.y)*s),(bf16)((x0.z+c0.z)*s),(bf16)((x0.w+c0.w)*s),
                         (bf16)((x1.x+c1.x)*s),(bf16)((x1.y+c1.y)*s),(bf16)((x1.z+c1.z)*s),(bf16)((x1.w+c1.w)*s)};
            bf16x8 v1 = {(bf16)((x2.x+c2.x)*s),(bf16)((x2.y+c2.y)*s),(bf16)((x2.z+c2.z)*s),(bf16)((x2.w+c2.w)*s),
                         (bf16)((x3.x+c3.x)*s),(bf16)((x3.y+c3.y)*s),(bf16)((x3.z+c3.z)*s),(bf16)((x3.w+c3.w)*s)};
            *(bf16x8*)(As + ar * 32 + ac) = v0;
            *(bf16x8*)(As + ar * 32 + ac + 8) = v1;
        }
        __syncthreads();
        bf16x8 fa[4], fb[4];
        #pragma unroll
        for (int mf = 0; mf < 4; mf++)
            fa[mf] = *(const bf16x8*)(As + (wm * 64 + mf * 16 + fr) * 32 + quad * 8);
        #pragma unroll
        for (int nf = 0; nf < 4; nf++)
            fb[nf] = *(const bf16x8*)(Bs + (wn * 64 + nf * 16 + fr) * 32 + quad * 8);
        #pragma unroll
        for (int mf = 0; mf < 4; mf++)
            #pragma unroll
            for (int nf = 0; nf < 4; nf++)
                acc[mf][nf] = __builtin_amdgcn_mfma_f32_16x16x32_bf16(fa[mf], fb[nf], acc[mf][nf], 0, 0, 0);
    }
    #pragma unroll
    for (int nf = 0; nf < 4; nf++) {
        const int col = o0 + wn * 64 + nf * 16 + fr;
        const float bs = bp[col];
        #pragma unroll
        for (int mf = 0; mf < 4; mf++) {
            const int row = i0 + wm * 64 + mf * 16 + quad * 4;
            #pragma unroll
            for (int r = 0; r < 4; r++)
                out[(size_t)(row + r) * D + col] = fmaxf(acc[mf][nf][r] + bs, 0.f);
        }
    }
}

extern "C" void kernel_launch(void* const* d_in, const int* in_sizes, int n_in,
                              void* d_out, int out_size, void* d_ws, size_t ws_size,
                              hipStream_t stream) {
    const float* nf    = (const float*)d_in[0];
    const int*   batch = (const int*)d_in[1];
    const float* gq    = (const float*)d_in[2];
    const float* wq    = (const float*)d_in[3];
    const float* bq    = (const float*)d_in[4];
    const float* wk    = (const float*)d_in[5];
    const float* bk    = (const float*)d_in[6];
    const float* wv    = (const float*)d_in[7];
    const float* bv    = (const float*)d_in[8];
    const float* wo    = (const float*)d_in[9];
    const float* bo    = (const float*)d_in[10];
    const float* wp    = (const float*)d_in[11];
    const float* bp    = (const float*)d_in[12];
    float* out = (float*)d_out;

    // workspace layout:
    // [0, 64Mi): Abf during cvt_a..k_gemm; afterwards recycled:
    //   abar [2Mi,6Mi) | Wov [6Mi,10Mi) | tmp [10Mi,11Mi) | cst [11Mi,+4K)
    // [64Mi,128Mi): Kb.  [128Mi, ...): lb, udata, Wkb, Wpb, P2.
    char* ws = (char*)d_ws;
    bf16*  Abf  = (bf16*)ws;
    bf16*  abar = (bf16*)(ws + ((size_t)2 << 20));
    bf16*  Wov  = (bf16*)(ws + ((size_t)6 << 20));
    float* tmp  = (float*)(ws + ((size_t)10 << 20));
    float* cst  = (float*)(ws + ((size_t)11 << 20));
    bf16*  Kb   = (bf16*)(ws + ((size_t)64 << 20));
    char* sm = ws + ((size_t)128 << 20);
    int*  lb    = (int*)sm;    sm += 4096;
    int*  udata = (int*)sm;    sm += (size_t)NUM_GRAPHS * USTRIDE * 4 + 2048;
    bf16* Wkb   = (bf16*)sm;   sm += (size_t)D * D * 2;
    bf16* Wpb   = (bf16*)sm;   sm += (size_t)D * D * 2;
    float* P2   = (float*)sm;  sm += (size_t)64 * D * 4;

    lb_kernel<<<3, 256, 0, stream>>>(batch, lb);
    dedup_kernel<<<NUM_GRAPHS, 192, 0, stream>>>(lb, udata);
    cvt_kernel<<<(D * D / 4) / 256, 256, 0, stream>>>(wk, Wkb, D * D);
    cvt_kernel<<<(D * D / 4) / 256, 256, 0, stream>>>(wp, Wpb, D * D);
    p2_kernel<<<dim3(8, 8), 256, 0, stream>>>(gq, wq, P2);
    cvt_kernel<<<(N_NODES * D / 4) / 256, 256, 0, stream>>>(nf, Abf, N_NODES * D);
    k_gemm<<<2048, 256, 0, stream>>>(Abf, Wkb, bk, Kb);
    // Abf dead; region recycled for abar/Wov/tmp/cst
    wov_kernel<<<dim3(16, 8), 256, 0, stream>>>(wo, wv, Wov);
    cst_kernel<<<2, 256, 0, stream>>>(wo, bv, bo, cst);
    attn_kernel<<<NUM_GRAPHS, 512, 0, stream>>>(Kb, P2, bq, lb, udata, nf, abar);
    zero_kernel<<<(NUM_GRAPHS * D / 4 + 255) / 256, 256, 0, stream>>>(tmp, NUM_GRAPHS * D / 4);
    og_gemm<<<dim3(4, 4, 8), 256, 0, stream>>>(abar, Wov, tmp);
    proj_p<<<dim3(4, 4), 256, 0, stream>>>(tmp, cst, Wpb, bp, lb, out);
}

// Round 5
// 448.052 us; speedup vs baseline: 1.0034x; 1.0034x over previous
//
#include <hip/hip_runtime.h>
#include <hip/hip_bf16.h>
#include <cstdint>

typedef __bf16 bf16;
typedef __attribute__((ext_vector_type(8))) __bf16 bf16x8;
typedef __attribute__((ext_vector_type(4))) __bf16 bf16x4;
typedef __attribute__((ext_vector_type(2))) __bf16 bf16x2;
typedef __attribute__((ext_vector_type(4))) float f32x4;

#define N_NODES    65536
#define NUM_GRAPHS 512
#define MAX_N      192
#define D          512
#define H          8
#define DH         64
#define UMAX       64
#define USTRIDE    132

__device__ __forceinline__ void gload_lds16(const void* g, void* l) {
    __builtin_amdgcn_global_load_lds((const __attribute__((address_space(1))) void*)g,
                                     (__attribute__((address_space(3))) void*)l, 16, 0, 0);
}

// ---------------- kernel: graph boundaries ----------------
__global__ __launch_bounds__(256) void lb_kernel(const int* __restrict__ batch,
                                                 int* __restrict__ lb) {
    int g = blockIdx.x * 256 + threadIdx.x;
    if (g > NUM_GRAPHS) return;
    int lo = 0, hi = N_NODES;
    while (lo < hi) {
        int mid = (lo + hi) >> 1;
        if (batch[mid] < g) lo = mid + 1; else hi = mid;
    }
    lb[g] = lo;
}

// ---------------- kernel: per-graph unique Q-row patterns ----------------
// serial pass runs entirely in LDS (was: ~192 dependent global RMWs).
__global__ __launch_bounds__(192) void dedup_kernel(const int* __restrict__ lb,
                                                    int* __restrict__ udata) {
    const int g = blockIdx.x;
    const int off = lb[g];
    const int n = min(lb[g + 1] - off, MAX_N);
    __shared__ int keys[MAX_N];
    __shared__ int ukey[UMAX], ucnt[UMAX];
    __shared__ int nu_s;
    const int t = threadIdx.x;
    if (t < n) {
        unsigned un = (unsigned)n;
        int key = 0;
        #pragma unroll
        for (int p = 0; p < 8; p++) key |= (int)(((unsigned)(8 * t + p)) / un) << (3 * p);
        keys[t] = key;
    }
    __syncthreads();
    if (t == 0) {
        int nu = 0;
        for (int s = 0; s < n; s++) {
            if (s == 0 || keys[s] != keys[s - 1]) {
                if (nu < UMAX) { ukey[nu] = keys[s]; ucnt[nu] = 0; nu++; }
            }
            ucnt[nu - 1] += 1;
        }
        nu_s = nu;
    }
    __syncthreads();
    const int nu = nu_s;
    int* base = udata + (size_t)g * USTRIDE;
    if (t == 0) base[0] = nu;
    if (t < nu) { base[1 + t] = ukey[t]; base[65 + t] = ucnt[t]; }
}

// ---------------- kernel: fp32 -> bf16 convert ----------------
__global__ __launch_bounds__(256) void cvt_kernel(const float* __restrict__ src,
                                                  bf16* __restrict__ dst, int n) {
    int i = (blockIdx.x * 256 + threadIdx.x) * 4;
    if (i >= n) return;
    float4 v = *(const float4*)(src + i);
    bf16x4 o = {(bf16)v.x, (bf16)v.y, (bf16)v.z, (bf16)v.w};
    *(bf16x4*)(dst + i) = o;
}

// ---------------- kernel: P2[h][p][o] = sum_j gq[h*64+j]*wq[o,64p+j] ----------------
__global__ __launch_bounds__(256) void p2_kernel(const float* __restrict__ gq,
                                                 const float* __restrict__ wq,
                                                 float* __restrict__ P2) {
    int h = blockIdx.x, p = blockIdx.y;
    __shared__ float gs[64];
    if (threadIdx.x < 64) gs[threadIdx.x] = gq[h * 64 + threadIdx.x];
    __syncthreads();
    for (int o = threadIdx.x; o < D; o += 256) {
        const float* wr = wq + (size_t)o * D + p * 64;
        float acc = 0.f;
        #pragma unroll 16
        for (int j = 0; j < 64; j++) acc += gs[j] * wr[j];
        P2[(size_t)(h * 8 + p) * D + o] = acc;
    }
}

// ---------------- kernel: Wov[o, h*512+d'] = sum_j wo[o,h*64+j]*wv[h*64+j,d'] ----------------
__global__ __launch_bounds__(256) void wov_kernel(const float* __restrict__ wo,
                                                  const float* __restrict__ wv,
                                                  bf16* __restrict__ Wov) {
    const int ot = blockIdx.x;   // o block of 32
    const int h  = blockIdx.y;
    __shared__ float wos[32 * 64];
    for (int idx = threadIdx.x; idx < 32 * 64; idx += 256) {
        int ol = idx >> 6, j = idx & 63;
        wos[idx] = wo[(size_t)(ot * 32 + ol) * D + h * 64 + j];
    }
    __syncthreads();
    const int c = threadIdx.x * 2;
    float acc0[32] = {}, acc1[32] = {};
    for (int j = 0; j < 64; j++) {
        float2 v2 = *(const float2*)(wv + (size_t)(h * 64 + j) * D + c);
        #pragma unroll
        for (int o = 0; o < 32; o++) {
            float wj = wos[o * 64 + j];
            acc0[o] += wj * v2.x; acc1[o] += wj * v2.y;
        }
    }
    #pragma unroll
    for (int o = 0; o < 32; o++) {
        bf16x2 r = {(bf16)acc0[o], (bf16)acc1[o]};
        *(bf16x2*)(Wov + (size_t)(ot * 32 + o) * 4096 + h * 512 + c) = r;
    }
}

// ---------------- kernel: cst[o] = wo[o,:].bv + bo[o] ----------------
__global__ __launch_bounds__(256) void cst_kernel(const float* __restrict__ wo,
                                                  const float* __restrict__ bv,
                                                  const float* __restrict__ bo,
                                                  float* __restrict__ cst) {
    int o = blockIdx.x * 256 + threadIdx.x;
    if (o >= D) return;
    const float* wr = wo + (size_t)o * D;
    float acc = bo[o];
    for (int d0 = 0; d0 < D; d0 += 4) {
        float4 wv4 = *(const float4*)(wr + d0);
        float4 b4  = *(const float4*)(bv + d0);
        acc += wv4.x * b4.x + wv4.y * b4.y + wv4.z * b4.z + wv4.w * b4.w;
    }
    cst[o] = acc;
}

// ---------------- kernel: K GEMM, 128x128 tile ----------------
// global_load_lds both operands, linear [128][32] LDS (measured fastest;
// reg-staging was +40% slower) + XCD-swizzled grid (A slab L2-resident
// across its 4 n-tile users) + LDS-staged epilogue (coalesced 16B stores).
__global__ __launch_bounds__(256) void k_gemm(const bf16* __restrict__ Ab,
                                              const bf16* __restrict__ Wkb,
                                              const float* __restrict__ bkb,
                                              bf16* __restrict__ Kout) {
    const int lin = blockIdx.x;          // 0..2047
    const int xcd = lin & 7;
    const int idx = lin >> 3;            // 0..255
    const int nt  = idx & 3;             // n-tile fast within XCD
    const int ml  = idx >> 2;            // 0..63
    const int i0 = (xcd * 64 + ml) * 128;
    const int o0 = nt * 128;

    __shared__ char smem[16896];         // As[128][32]@0 | Bs[128][32]@8192; Cs[64][132] overlays
    bf16* As = (bf16*)smem;
    bf16* Bs = (bf16*)(smem + 8192);
    const int tid = threadIdx.x;
    const int lane = tid & 63;
    const int w = tid >> 6;
    const int wm = w & 1, wn = w >> 1;
    const int fr = lane & 15, quad = lane >> 4;
    const bf16* gA = Ab + (size_t)(i0 + w * 32 + (lane >> 2)) * D + (lane & 3) * 8;
    const bf16* gB = Wkb + (size_t)(o0 + w * 32 + (lane >> 2)) * D + (lane & 3) * 8;
    bf16* lA = As + (w * 32) * 32;
    bf16* lB = Bs + (w * 32) * 32;

    f32x4 acc[4][4] = {};

    for (int kt = 0; kt < D; kt += 32) {
        __syncthreads();
        gload_lds16(gA + kt, lA);
        gload_lds16(gA + (size_t)16 * D + kt, lA + 16 * 32);
        gload_lds16(gB + kt, lB);
        gload_lds16(gB + (size_t)16 * D + kt, lB + 16 * 32);
        __syncthreads();
        bf16x8 fa[4], fb[4];
        #pragma unroll
        for (int mf = 0; mf < 4; mf++)
            fa[mf] = *(const bf16x8*)(As + (wm * 64 + mf * 16 + fr) * 32 + quad * 8);
        #pragma unroll
        for (int nf = 0; nf < 4; nf++)
            fb[nf] = *(const bf16x8*)(Bs + (wn * 64 + nf * 16 + fr) * 32 + quad * 8);
        #pragma unroll
        for (int mf = 0; mf < 4; mf++)
            #pragma unroll
            for (int nf = 0; nf < 4; nf++)
                acc[mf][nf] = __builtin_amdgcn_mfma_f32_16x16x32_bf16(fa[mf], fb[nf], acc[mf][nf], 0, 0, 0);
    }

    // epilogue: stage each 64-row half in LDS (stride 132 -> conflict-free),
    // then coalesced bf16x8 stores.
    bf16* Cs = (bf16*)smem;
    #pragma unroll
    for (int pass = 0; pass < 2; pass++) {
        __syncthreads();
        if (wm == pass) {
            #pragma unroll
            for (int nf = 0; nf < 4; nf++) {
                const int col = wn * 64 + nf * 16 + fr;
                const float bs = bkb[o0 + col];
                #pragma unroll
                for (int mf = 0; mf < 4; mf++) {
                    #pragma unroll
                    for (int r = 0; r < 4; r++)
                        Cs[(mf * 16 + quad * 4 + r) * 132 + col] = (bf16)(acc[mf][nf][r] + bs);
                }
            }
        }
        __syncthreads();
        #pragma unroll
        for (int k = 0; k < 4; k++) {
            int idx2 = k * 256 + tid;            // 0..1023
            int row = idx2 >> 4;                 // 0..63
            int coff = (idx2 & 15) * 8;          // 0..120
            bf16x8 v = *(const bf16x8*)(Cs + row * 132 + coff);
            *(bf16x8*)(Kout + (size_t)(i0 + pass * 64 + row) * D + o0 + coff) = v;
        }
    }
}

// ---------------- kernel: attention + fused abar ----------------
// grid NUM_GRAPHS blocks x 512 threads; wave w == head h.  K is read inside
// the c0 loop (L1/L2-served, only ~4 re-reads of a 24KB tile) -- hoisting K
// into registers (+96 VGPR) halved occupancy and cost ~30us net (round-4
// lesson: price the VGPR side of reuse trades).  abar phase: thread tid owns
// output column tid for all 8 heads.
__global__ __launch_bounds__(512) void attn_kernel(const bf16* __restrict__ Kb,
                                                   const float* __restrict__ P2,
                                                   const float* __restrict__ bq,
                                                   const int* __restrict__ lb,
                                                   const int* __restrict__ udata,
                                                   const float* __restrict__ Af,
                                                   bf16* __restrict__ abar) {
    const int g = blockIdx.x;
    const int tid = threadIdx.x;
    const int lane = tid & 63;
    const int w = tid >> 6;          // 0..7 == head
    const int h = w;
    const int off = lb[g];
    const int n = min(lb[g + 1] - off, MAX_N);

    __shared__ bf16 Qs[8][16 * 80];
    __shared__ float wacc[8][MAX_N];
    __shared__ int upat_l[UMAX], ucnt_l[UMAX];

    bf16* outg = abar + (size_t)g * 4096;
    if (n == 0) {
        const bf16 z0 = (bf16)0.f;
        bf16x8 z = {z0, z0, z0, z0, z0, z0, z0, z0};
        *(bf16x8*)(outg + tid * 8) = z;
        return;
    }

    const int* ubase = udata + (size_t)g * USTRIDE;
    const int nu = ubase[0];
    if (tid < 64) {
        upat_l[tid] = (tid < nu) ? ubase[1 + tid] : 0;
        ucnt_l[tid] = (tid < nu) ? ubase[65 + tid] : 0;
    }
    wacc[w][lane] = 0.f; wacc[w][64 + lane] = 0.f; wacc[w][128 + lane] = 0.f;
    __syncthreads();

    const int fr = lane & 15;
    const int quad = lane >> 4;
    const float inv_n = 1.0f / (float)n;

    for (int c0 = 0; c0 < nu; c0 += 16) {
        {   // build 16 Q rows (bf16) in wave-private LDS
            const int ul = lane >> 2;
            const int j0 = (lane & 3) * 16;
            const bool valid = (c0 + ul) < nu;
            const int pat = upat_l[c0 + ul];
            const float* bpq = bq + h * 64 + j0;
            float4 q0 = *(const float4*)bpq;
            float4 q1 = *(const float4*)(bpq + 4);
            float4 q2 = *(const float4*)(bpq + 8);
            float4 q3 = *(const float4*)(bpq + 12);
            #pragma unroll
            for (int p = 0; p < 8; p++) {
                const int hp = (pat >> (3 * p)) & 7;
                const float* pp = P2 + (size_t)(hp * 8 + p) * D + h * 64 + j0;
                float4 t0 = *(const float4*)pp;
                float4 t1 = *(const float4*)(pp + 4);
                float4 t2 = *(const float4*)(pp + 8);
                float4 t3 = *(const float4*)(pp + 12);
                q0.x += t0.x; q0.y += t0.y; q0.z += t0.z; q0.w += t0.w;
                q1.x += t1.x; q1.y += t1.y; q1.z += t1.z; q1.w += t1.w;
                q2.x += t2.x; q2.y += t2.y; q2.z += t2.z; q2.w += t2.w;
                q3.x += t3.x; q3.y += t3.y; q3.z += t3.z; q3.w += t3.w;
            }
            if (!valid) {
                q0.x=q0.y=q0.z=q0.w=0.f; q1.x=q1.y=q1.z=q1.w=0.f;
                q2.x=q2.y=q2.z=q2.w=0.f; q3.x=q3.y=q3.z=q3.w=0.f;
            }
            bf16x8 b0 = {(bf16)q0.x,(bf16)q0.y,(bf16)q0.z,(bf16)q0.w,
                         (bf16)q1.x,(bf16)q1.y,(bf16)q1.z,(bf16)q1.w};
            bf16x8 b1 = {(bf16)q2.x,(bf16)q2.y,(bf16)q2.z,(bf16)q2.w,
                         (bf16)q3.x,(bf16)q3.y,(bf16)q3.z,(bf16)q3.w};
            *(bf16x8*)(&Qs[w][ul * 80 + j0])     = b0;
            *(bf16x8*)(&Qs[w][ul * 80 + j0 + 8]) = b1;
        }
        bf16x8 fa0 = *(const bf16x8*)(&Qs[w][fr * 80 + quad * 8]);
        bf16x8 fa1 = *(const bf16x8*)(&Qs[w][fr * 80 + 32 + quad * 8]);

        f32x4 sc[12];
        #pragma unroll
        for (int st = 0; st < 12; st++) {
            if (st * 16 < n) {
                int s = st * 16 + fr;
                int row = off + (s < n ? s : n - 1);
                const bf16* kp = Kb + (size_t)row * D + h * 64 + quad * 8;
                bf16x8 fb0 = *(const bf16x8*)kp;
                bf16x8 fb1 = *(const bf16x8*)(kp + 32);
                f32x4 a = {0.f, 0.f, 0.f, 0.f};
                a = __builtin_amdgcn_mfma_f32_16x16x32_bf16(fa0, fb0, a, 0, 0, 0);
                a = __builtin_amdgcn_mfma_f32_16x16x32_bf16(fa1, fb1, a, 0, 0, 0);
                if (s < n) {
                    sc[st].x = a.x * 0.125f; sc[st].y = a.y * 0.125f;
                    sc[st].z = a.z * 0.125f; sc[st].w = a.w * 0.125f;
                } else {
                    sc[st].x = sc[st].y = sc[st].z = sc[st].w = -1e30f;
                }
            } else {
                sc[st].x = sc[st].y = sc[st].z = sc[st].w = -1e30f;
            }
        }
        float m[4] = {-1e30f, -1e30f, -1e30f, -1e30f};
        #pragma unroll
        for (int st = 0; st < 12; st++) {
            m[0] = fmaxf(m[0], sc[st].x); m[1] = fmaxf(m[1], sc[st].y);
            m[2] = fmaxf(m[2], sc[st].z); m[3] = fmaxf(m[3], sc[st].w);
        }
        #pragma unroll
        for (int o = 1; o <= 8; o <<= 1) {
            #pragma unroll
            for (int r = 0; r < 4; r++) m[r] = fmaxf(m[r], __shfl_xor(m[r], o));
        }
        float den[4] = {0.f, 0.f, 0.f, 0.f};
        #pragma unroll
        for (int st = 0; st < 12; st++) {
            float e0 = __expf(sc[st].x - m[0]); float e1 = __expf(sc[st].y - m[1]);
            float e2 = __expf(sc[st].z - m[2]); float e3 = __expf(sc[st].w - m[3]);
            sc[st].x = e0; sc[st].y = e1; sc[st].z = e2; sc[st].w = e3;
            den[0] += e0; den[1] += e1; den[2] += e2; den[3] += e3;
        }
        #pragma unroll
        for (int o = 1; o <= 8; o <<= 1) {
            #pragma unroll
            for (int r = 0; r < 4; r++) den[r] += __shfl_xor(den[r], o);
        }
        float wf[4];
        #pragma unroll
        for (int r = 0; r < 4; r++)
            wf[r] = (float)ucnt_l[c0 + quad * 4 + r] * inv_n / den[r];
        #pragma unroll
        for (int st = 0; st < 12; st++) {
            float v = sc[st].x * wf[0] + sc[st].y * wf[1] + sc[st].z * wf[2] + sc[st].w * wf[3];
            v += __shfl_xor(v, 16);
            v += __shfl_xor(v, 32);
            if (lane < 16) wacc[w][st * 16 + lane] += v;
        }
    }

    // ---- fused abar: thread tid owns column tid for all 8 heads ----
    __syncthreads();
    const float* Ac = Af + (size_t)off * D + tid;
    float accv[8] = {};
    for (int s = 0; s < n; s++) {
        float av = Ac[(size_t)s * D];
        #pragma unroll
        for (int hh = 0; hh < 8; hh++) accv[hh] += wacc[hh][s] * av;
    }
    #pragma unroll
    for (int hh = 0; hh < 8; hh++) outg[hh * 512 + tid] = (bf16)accv[hh];
}

// ---------------- kernel: zero tmp ----------------
__global__ __launch_bounds__(256) void zero_kernel(float* __restrict__ p, int n4) {
    int i = blockIdx.x * 256 + threadIdx.x;
    if (i < n4) { float4 z = {0.f, 0.f, 0.f, 0.f}; *(float4*)(p + i * 4) = z; }
}

// ---------------- kernel: fused Wov GEMM, M=512 N=512 K=4096, split-K atomics ----------------
__global__ __launch_bounds__(256) void og_gemm(const bf16* __restrict__ Ab,
                                               const bf16* __restrict__ Bb,
                                               float* __restrict__ Yt) {
    const int o0 = blockIdx.x * 128;
    const int i0 = blockIdx.y * 128;
    const int k0 = blockIdx.z * 512;
    __shared__ bf16 As[128 * 32];
    __shared__ bf16 Bs[128 * 32];
    const int tid = threadIdx.x;
    const int lane = tid & 63;
    const int w = tid >> 6;
    const int wm = w & 1, wn = w >> 1;
    const int fr = lane & 15, quad = lane >> 4;
    const bf16* gA = Ab + (size_t)(i0 + w * 32 + (lane >> 2)) * 4096 + k0 + (lane & 3) * 8;
    const bf16* gB = Bb + (size_t)(o0 + w * 32 + (lane >> 2)) * 4096 + k0 + (lane & 3) * 8;
    bf16* lA = As + (w * 32) * 32;
    bf16* lB = Bs + (w * 32) * 32;

    f32x4 acc[4][4] = {};

    for (int kt = 0; kt < 512; kt += 32) {
        __syncthreads();
        gload_lds16(gA + kt, lA);
        gload_lds16(gA + (size_t)16 * 4096 + kt, lA + 16 * 32);
        gload_lds16(gB + kt, lB);
        gload_lds16(gB + (size_t)16 * 4096 + kt, lB + 16 * 32);
        __syncthreads();
        bf16x8 fa[4], fb[4];
        #pragma unroll
        for (int mf = 0; mf < 4; mf++)
            fa[mf] = *(const bf16x8*)(As + (wm * 64 + mf * 16 + fr) * 32 + quad * 8);
        #pragma unroll
        for (int nf = 0; nf < 4; nf++)
            fb[nf] = *(const bf16x8*)(Bs + (wn * 64 + nf * 16 + fr) * 32 + quad * 8);
        #pragma unroll
        for (int mf = 0; mf < 4; mf++)
            #pragma unroll
            for (int nf = 0; nf < 4; nf++)
                acc[mf][nf] = __builtin_amdgcn_mfma_f32_16x16x32_bf16(fa[mf], fb[nf], acc[mf][nf], 0, 0, 0);
    }
    #pragma unroll
    for (int nf = 0; nf < 4; nf++) {
        const int col = o0 + wn * 64 + nf * 16 + fr;
        #pragma unroll
        for (int mf = 0; mf < 4; mf++) {
            const int row = i0 + wm * 64 + mf * 16 + quad * 4;
            #pragma unroll
            for (int r = 0; r < 4; r++)
                atomicAdd(&Yt[(size_t)(row + r) * D + col], acc[mf][nf][r]);
        }
    }
}

// ---------------- kernel: final projection out = relu((tmp+cst|0) @ Wp^T + bp) ----------------
__global__ __launch_bounds__(256) void proj_p(const float* __restrict__ tmp,
                                              const float* __restrict__ cst,
                                              const bf16* __restrict__ Wpb,
                                              const float* __restrict__ bp,
                                              const int* __restrict__ lb,
                                              float* __restrict__ out) {
    const int o0 = blockIdx.x * 128;
    const int i0 = blockIdx.y * 128;
    __shared__ bf16 As[128 * 32];
    __shared__ bf16 Bs[128 * 32];
    const int tid = threadIdx.x;
    const int lane = tid & 63;
    const int w = tid >> 6;
    const int wm = w & 1, wn = w >> 1;
    const int fr = lane & 15, quad = lane >> 4;
    const int ar = tid >> 1;
    const int ac = (tid & 1) * 16;
    const int g = i0 + ar;
    const bool live = lb[g + 1] - lb[g] > 0;
    const float* tp = tmp + (size_t)g * D + ac;
    const float* cp = cst + ac;
    const bf16* gB = Wpb + (size_t)(o0 + w * 32 + (lane >> 2)) * D + (lane & 3) * 8;
    bf16* lB = Bs + (w * 32) * 32;

    f32x4 acc[4][4] = {};

    for (int kt = 0; kt < D; kt += 32) {
        __syncthreads();
        gload_lds16(gB + kt, lB);
        gload_lds16(gB + (size_t)16 * D + kt, lB + 16 * 32);
        {
            float4 x0 = *(const float4*)(tp + kt);
            float4 x1 = *(const float4*)(tp + kt + 4);
            float4 x2 = *(const float4*)(tp + kt + 8);
            float4 x3 = *(const float4*)(tp + kt + 12);
            float4 c0 = *(const float4*)(cp + kt);
            float4 c1 = *(const float4*)(cp + kt + 4);
            float4 c2 = *(const float4*)(cp + kt + 8);
            float4 c3 = *(const float4*)(cp + kt + 12);
            float s = live ? 1.f : 0.f;
            bf16x8 v0 = {(bf16)((x0.x+c0.x)*s),(bf16)((x0.y+c0.y)*s),(bf16)((x0.z+c0.z)*s),(bf16)((x0.w+c0.w)*s),
                         (bf16)((x1.x+c1.x)*s),(bf16)((x1.y+c1.y)*s),(bf16)((x1.z+c1.z)*s),(bf16)((x1.w+c1.w)*s)};
            bf16x8 v1 = {(bf16)((x2.x+c2.x)*s),(bf16)((x2.y+c2.y)*s),(bf16)((x2.z+c2.z)*s),(bf16)((x2.w+c2.w)*s),
                         (bf16)((x3.x+c3.x)*s),(bf16)((x3.y+c3.y)*s),(bf16)((x3.z+c3.z)*s),(bf16)((x3.w+c3.w)*s)};
            *(bf16x8*)(As + ar * 32 + ac) = v0;
            *(bf16x8*)(As + ar * 32 + ac + 8) = v1;
        }
        __syncthreads();
        bf16x8 fa[4], fb[4];
        #pragma unroll
        for (int mf = 0; mf < 4; mf++)
            fa[mf] = *(const bf16x8*)(As + (wm * 64 + mf * 16 + fr) * 32 + quad * 8);
        #pragma unroll
        for (int nf = 0; nf < 4; nf++)
            fb[nf] = *(const bf16x8*)(Bs + (wn * 64 + nf * 16 + fr) * 32 + quad * 8);
        #pragma unroll
        for (int mf = 0; mf < 4; mf++)
            #pragma unroll
            for (int nf = 0; nf < 4; nf++)
                acc[mf][nf] = __builtin_amdgcn_mfma_f32_16x16x32_bf16(fa[mf], fb[nf], acc[mf][nf], 0, 0, 0);
    }
    #pragma unroll
    for (int nf = 0; nf < 4; nf++) {
        const int col = o0 + wn * 64 + nf * 16 + fr;
        const float bs = bp[col];
        #pragma unroll
        for (int mf = 0; mf < 4; mf++) {
            const int row = i0 + wm * 64 + mf * 16 + quad * 4;
            #pragma unroll
            for (int r = 0; r < 4; r++)
                out[(size_t)(row + r) * D + col] = fmaxf(acc[mf][nf][r] + bs, 0.f);
        }
    }
}

extern "C" void kernel_launch(void* const* d_in, const int* in_sizes, int n_in,
                              void* d_out, int out_size, void* d_ws, size_t ws_size,
                              hipStream_t stream) {
    const float* nf    = (const float*)d_in[0];
    const int*   batch = (const int*)d_in[1];
    const float* gq    = (const float*)d_in[2];
    const float* wq    = (const float*)d_in[3];
    const float* bq    = (const float*)d_in[4];
    const float* wk    = (const float*)d_in[5];
    const float* bk    = (const float*)d_in[6];
    const float* wv    = (const float*)d_in[7];
    const float* bv    = (const float*)d_in[8];
    const float* wo    = (const float*)d_in[9];
    const float* bo    = (const float*)d_in[10];
    const float* wp    = (const float*)d_in[11];
    const float* bp    = (const float*)d_in[12];
    float* out = (float*)d_out;

    // workspace layout:
    // [0, 64Mi): Abf during cvt_a..k_gemm; afterwards recycled:
    //   abar [2Mi,6Mi) | Wov [6Mi,10Mi) | tmp [10Mi,11Mi) | cst [11Mi,+4K)
    // [64Mi,128Mi): Kb.  [128Mi, ...): lb, udata, Wkb, Wpb, P2.
    char* ws = (char*)d_ws;
    bf16*  Abf  = (bf16*)ws;
    bf16*  abar = (bf16*)(ws + ((size_t)2 << 20));
    bf16*  Wov  = (bf16*)(ws + ((size_t)6 << 20));
    float* tmp  = (float*)(ws + ((size_t)10 << 20));
    float* cst  = (float*)(ws + ((size_t)11 << 20));
    bf16*  Kb   = (bf16*)(ws + ((size_t)64 << 20));
    char* sm = ws + ((size_t)128 << 20);
    int*  lb    = (int*)sm;    sm += 4096;
    int*  udata = (int*)sm;    sm += (size_t)NUM_GRAPHS * USTRIDE * 4 + 2048;
    bf16* Wkb   = (bf16*)sm;   sm += (size_t)D * D * 2;
    bf16* Wpb   = (bf16*)sm;   sm += (size_t)D * D * 2;
    float* P2   = (float*)sm;  sm += (size_t)64 * D * 4;

    lb_kernel<<<3, 256, 0, stream>>>(batch, lb);
    dedup_kernel<<<NUM_GRAPHS, 192, 0, stream>>>(lb, udata);
    cvt_kernel<<<(D * D / 4) / 256, 256, 0, stream>>>(wk, Wkb, D * D);
    cvt_kernel<<<(D * D / 4) / 256, 256, 0, stream>>>(wp, Wpb, D * D);
    p2_kernel<<<dim3(8, 8), 256, 0, stream>>>(gq, wq, P2);
    cvt_kernel<<<(N_NODES * D / 4) / 256, 256, 0, stream>>>(nf, Abf, N_NODES * D);
    k_gemm<<<2048, 256, 0, stream>>>(Abf, Wkb, bk, Kb);
    // Abf dead; region recycled for abar/Wov/tmp/cst
    wov_kernel<<<dim3(16, 8), 256, 0, stream>>>(wo, wv, Wov);
    cst_kernel<<<2, 256, 0, stream>>>(wo, bv, bo, cst);
    attn_kernel<<<NUM_GRAPHS, 512, 0, stream>>>(Kb, P2, bq, lb, udata, nf, abar);
    zero_kernel<<<(NUM_GRAPHS * D / 4 + 255) / 256, 256, 0, stream>>>(tmp, NUM_GRAPHS * D / 4);
    og_gemm<<<dim3(4, 4, 8), 256, 0, stream>>>(abar, Wov, tmp);
    proj_p<<<dim3(4, 4), 256, 0, stream>>>(tmp, cst, Wpb, bp, lb, out);
}

// Round 6
// 436.496 us; speedup vs baseline: 1.0299x; 1.0265x over previous
//
#include <hip/hip_runtime.h>
#include <hip/hip_bf16.h>
#include <cstdint>

typedef __bf16 bf16;
typedef __attribute__((ext_vector_type(8))) __bf16 bf16x8;
typedef __attribute__((ext_vector_type(4))) __bf16 bf16x4;
typedef __attribute__((ext_vector_type(2))) __bf16 bf16x2;
typedef __attribute__((ext_vector_type(4))) float f32x4;

#define N_NODES    65536
#define NUM_GRAPHS 512
#define MAX_N      192
#define D          512
#define H          8
#define DH         64
#define UMAX       64
#define USTRIDE    132

__device__ __forceinline__ void gload_lds16(const void* g, void* l) {
    __builtin_amdgcn_global_load_lds((const __attribute__((address_space(1))) void*)g,
                                     (__attribute__((address_space(3))) void*)l, 16, 0, 0);
}

// ---------------- kernel: graph boundaries ----------------
__global__ __launch_bounds__(256) void lb_kernel(const int* __restrict__ batch,
                                                 int* __restrict__ lb) {
    int g = blockIdx.x * 256 + threadIdx.x;
    if (g > NUM_GRAPHS) return;
    int lo = 0, hi = N_NODES;
    while (lo < hi) {
        int mid = (lo + hi) >> 1;
        if (batch[mid] < g) lo = mid + 1; else hi = mid;
    }
    lb[g] = lo;
}

// ---------------- kernel: descending-n permutation (load balance for attn) ----
__global__ __launch_bounds__(512) void sortg_kernel(const int* __restrict__ lb,
                                                    int* __restrict__ perm) {
    __shared__ int hist[MAX_N + 1];
    __shared__ int base[MAX_N + 1];
    const int t = threadIdx.x;
    if (t <= MAX_N) hist[t] = 0;
    __syncthreads();
    const int n = min(lb[t + 1] - lb[t], MAX_N);
    atomicAdd(&hist[n], 1);
    __syncthreads();
    if (t == 0) {
        int acc = 0;
        for (int k = MAX_N; k >= 0; k--) { base[k] = acc; acc += hist[k]; }
    }
    __syncthreads();
    int pos = atomicAdd(&base[n], 1);
    perm[pos] = t;
}

// ---------------- kernel: per-graph unique Q-row patterns ----------------
__global__ __launch_bounds__(192) void dedup_kernel(const int* __restrict__ lb,
                                                    int* __restrict__ udata) {
    const int g = blockIdx.x;
    const int off = lb[g];
    const int n = min(lb[g + 1] - off, MAX_N);
    __shared__ int keys[MAX_N];
    __shared__ int ukey[UMAX], ucnt[UMAX];
    __shared__ int nu_s;
    const int t = threadIdx.x;
    if (t < n) {
        unsigned un = (unsigned)n;
        int key = 0;
        #pragma unroll
        for (int p = 0; p < 8; p++) key |= (int)(((unsigned)(8 * t + p)) / un) << (3 * p);
        keys[t] = key;
    }
    __syncthreads();
    if (t == 0) {
        int nu = 0;
        for (int s = 0; s < n; s++) {
            if (s == 0 || keys[s] != keys[s - 1]) {
                if (nu < UMAX) { ukey[nu] = keys[s]; ucnt[nu] = 0; nu++; }
            }
            ucnt[nu - 1] += 1;
        }
        nu_s = nu;
    }
    __syncthreads();
    const int nu = nu_s;
    int* base = udata + (size_t)g * USTRIDE;
    if (t == 0) base[0] = nu;
    if (t < nu) { base[1 + t] = ukey[t]; base[65 + t] = ucnt[t]; }
}

// ---------------- kernel: fp32 -> bf16 convert (weights only) ----------------
__global__ __launch_bounds__(256) void cvt_kernel(const float* __restrict__ src,
                                                  bf16* __restrict__ dst, int n) {
    int i = (blockIdx.x * 256 + threadIdx.x) * 4;
    if (i >= n) return;
    float4 v = *(const float4*)(src + i);
    bf16x4 o = {(bf16)v.x, (bf16)v.y, (bf16)v.z, (bf16)v.w};
    *(bf16x4*)(dst + i) = o;
}

// ---------------- kernel: P2[h][p][o] = sum_j gq[h*64+j]*wq[o,64p+j] ----------------
__global__ __launch_bounds__(256) void p2_kernel(const float* __restrict__ gq,
                                                 const float* __restrict__ wq,
                                                 float* __restrict__ P2) {
    int h = blockIdx.x, p = blockIdx.y;
    __shared__ float gs[64];
    if (threadIdx.x < 64) gs[threadIdx.x] = gq[h * 64 + threadIdx.x];
    __syncthreads();
    for (int o = threadIdx.x; o < D; o += 256) {
        const float* wr = wq + (size_t)o * D + p * 64;
        float acc = 0.f;
        #pragma unroll 16
        for (int j = 0; j < 64; j++) acc += gs[j] * wr[j];
        P2[(size_t)(h * 8 + p) * D + o] = acc;
    }
}

// ---------------- kernel: Wov[o, h*512+d'] = sum_j wo[o,h*64+j]*wv[h*64+j,d'] ----------------
__global__ __launch_bounds__(256) void wov_kernel(const float* __restrict__ wo,
                                                  const float* __restrict__ wv,
                                                  bf16* __restrict__ Wov) {
    const int ot = blockIdx.x;   // o block of 32
    const int h  = blockIdx.y;
    __shared__ float wos[32 * 64];
    for (int idx = threadIdx.x; idx < 32 * 64; idx += 256) {
        int ol = idx >> 6, j = idx & 63;
        wos[idx] = wo[(size_t)(ot * 32 + ol) * D + h * 64 + j];
    }
    __syncthreads();
    const int c = threadIdx.x * 2;
    float acc0[32] = {}, acc1[32] = {};
    for (int j = 0; j < 64; j++) {
        float2 v2 = *(const float2*)(wv + (size_t)(h * 64 + j) * D + c);
        #pragma unroll
        for (int o = 0; o < 32; o++) {
            float wj = wos[o * 64 + j];
            acc0[o] += wj * v2.x; acc1[o] += wj * v2.y;
        }
    }
    #pragma unroll
    for (int o = 0; o < 32; o++) {
        bf16x2 r = {(bf16)acc0[o], (bf16)acc1[o]};
        *(bf16x2*)(Wov + (size_t)(ot * 32 + o) * 4096 + h * 512 + c) = r;
    }
}

// ---------------- kernel: cst[o] = wo[o,:].bv + bo[o] ----------------
__global__ __launch_bounds__(256) void cst_kernel(const float* __restrict__ wo,
                                                  const float* __restrict__ bv,
                                                  const float* __restrict__ bo,
                                                  float* __restrict__ cst) {
    int o = blockIdx.x * 256 + threadIdx.x;
    if (o >= D) return;
    const float* wr = wo + (size_t)o * D;
    float acc = bo[o];
    for (int d0 = 0; d0 < D; d0 += 4) {
        float4 wv4 = *(const float4*)(wr + d0);
        float4 b4  = *(const float4*)(bv + d0);
        acc += wv4.x * b4.x + wv4.y * b4.y + wv4.z * b4.z + wv4.w * b4.w;
    }
    cst[o] = acc;
}

// ---------------- kernel: K GEMM, 128x128 tile, fp32-A direct ----------------
// A loaded fp32 via global_load_lds (16B = 4 floats/lane) -- removes the 192MB
// cvt(nf) pass entirely while keeping the verified-fast gload_lds barrier
// structure.  A's source column is pre-swizzled (c16 ^= row&7, linear LDS
// dest, same XOR on the ds_read) so fp32 row-stride-128B fragment reads stay
// conflict-free (rule #21: swizzle both sides or neither).  bf16 conversion
// happens after ds_read (same round-to-nearest as the old cvt pass ->
// bit-identical results).  XCD-swizzled grid + LDS-staged epilogue kept.
__global__ __launch_bounds__(256) void k_gemm(const float* __restrict__ Af,
                                              const bf16* __restrict__ Wkb,
                                              const float* __restrict__ bkb,
                                              bf16* __restrict__ Kout) {
    const int lin = blockIdx.x;          // 0..2047
    const int xcd = lin & 7;
    const int idx = lin >> 3;            // 0..255
    const int nt  = idx & 3;             // n-tile fast within XCD
    const int ml  = idx >> 2;            // 0..63
    const int i0 = (xcd * 64 + ml) * 128;
    const int o0 = nt * 128;

    __shared__ char smem[24576];         // Asf[128][32] f32 (16K) | Bs[128][32] bf16 (8K)
    float* Asf = (float*)smem;
    bf16*  Bs  = (bf16*)(smem + 16384);
    const int tid = threadIdx.x;
    const int lane = tid & 63;
    const int w = tid >> 6;
    const int wm = w & 1, wn = w >> 1;
    const int fr = lane & 15, quad = lane >> 4;

    // A staging: lane covers row (lane>>3) of an 8-row slab, 16B col unit (lane&7),
    // source col XOR-swizzled by row&7.
    const int sra = lane >> 3;                     // 0..7
    const int c16 = lane & 7;
    const int scol = ((c16 ^ sra) << 2);           // floats
    const float* gA = Af + (size_t)(i0 + w * 32 + sra) * D + scol;
    float* lAf = Asf + (w * 32) * 32;              // wave-uniform dest

    // B staging unchanged (bf16, linear)
    const bf16* gB = Wkb + (size_t)(o0 + w * 32 + (lane >> 2)) * D + (lane & 3) * 8;
    bf16* lB = Bs + (w * 32) * 32;

    f32x4 acc[4][4] = {};

    for (int kt = 0; kt < D; kt += 32) {
        __syncthreads();
        gload_lds16(gA + kt, lAf);
        gload_lds16(gA + (size_t)8  * D + kt, lAf + 8  * 32);
        gload_lds16(gA + (size_t)16 * D + kt, lAf + 16 * 32);
        gload_lds16(gA + (size_t)24 * D + kt, lAf + 24 * 32);
        gload_lds16(gB + kt, lB);
        gload_lds16(gB + (size_t)16 * D + kt, lB + 16 * 32);
        __syncthreads();
        bf16x8 fa[4], fb[4];
        #pragma unroll
        for (int mf = 0; mf < 4; mf++) {
            const int row = wm * 64 + mf * 16 + fr;
            const int u0 = (quad * 2) ^ (row & 7);
            const int u1 = (quad * 2 + 1) ^ (row & 7);
            f32x4 a0 = *(const f32x4*)(Asf + row * 32 + u0 * 4);
            f32x4 a1 = *(const f32x4*)(Asf + row * 32 + u1 * 4);
            bf16x8 v = {(bf16)a0.x,(bf16)a0.y,(bf16)a0.z,(bf16)a0.w,
                        (bf16)a1.x,(bf16)a1.y,(bf16)a1.z,(bf16)a1.w};
            fa[mf] = v;
        }
        #pragma unroll
        for (int nf = 0; nf < 4; nf++)
            fb[nf] = *(const bf16x8*)(Bs + (wn * 64 + nf * 16 + fr) * 32 + quad * 8);
        #pragma unroll
        for (int mf = 0; mf < 4; mf++)
            #pragma unroll
            for (int nf = 0; nf < 4; nf++)
                acc[mf][nf] = __builtin_amdgcn_mfma_f32_16x16x32_bf16(fa[mf], fb[nf], acc[mf][nf], 0, 0, 0);
    }

    // epilogue: stage each 64-row half in LDS (stride 132 -> conflict-free),
    // then coalesced bf16x8 stores.
    bf16* Cs = (bf16*)smem;
    #pragma unroll
    for (int pass = 0; pass < 2; pass++) {
        __syncthreads();
        if (wm == pass) {
            #pragma unroll
            for (int nf = 0; nf < 4; nf++) {
                const int col = wn * 64 + nf * 16 + fr;
                const float bs = bkb[o0 + col];
                #pragma unroll
                for (int mf = 0; mf < 4; mf++) {
                    #pragma unroll
                    for (int r = 0; r < 4; r++)
                        Cs[(mf * 16 + quad * 4 + r) * 132 + col] = (bf16)(acc[mf][nf][r] + bs);
                }
            }
        }
        __syncthreads();
        #pragma unroll
        for (int k = 0; k < 4; k++) {
            int idx2 = k * 256 + tid;            // 0..1023
            int row = idx2 >> 4;                 // 0..63
            int coff = (idx2 & 15) * 8;          // 0..120
            bf16x8 v = *(const bf16x8*)(Cs + row * 132 + coff);
            *(bf16x8*)(Kout + (size_t)(i0 + pass * 64 + row) * D + o0 + coff) = v;
        }
    }
}

// ---------------- kernel: attention + fused abar ----------------
// grid NUM_GRAPHS blocks x 512 threads; block processes graph perm[blockIdx]
// (descending-n order -> longest-first scheduling trims the makespan tail).
// wave w == head h.  K read inside the c0 loop (L1/L2-served).  abar phase:
// thread tid owns output column tid for all 8 heads.
__global__ __launch_bounds__(512) void attn_kernel(const bf16* __restrict__ Kb,
                                                   const float* __restrict__ P2,
                                                   const float* __restrict__ bq,
                                                   const int* __restrict__ lb,
                                                   const int* __restrict__ udata,
                                                   const float* __restrict__ Af,
                                                   const int* __restrict__ perm,
                                                   bf16* __restrict__ abar) {
    const int g = perm[blockIdx.x];
    const int tid = threadIdx.x;
    const int lane = tid & 63;
    const int w = tid >> 6;          // 0..7 == head
    const int h = w;
    const int off = lb[g];
    const int n = min(lb[g + 1] - off, MAX_N);

    __shared__ bf16 Qs[8][16 * 80];
    __shared__ float wacc[8][MAX_N];
    __shared__ int upat_l[UMAX], ucnt_l[UMAX];

    bf16* outg = abar + (size_t)g * 4096;
    if (n == 0) {
        const bf16 z0 = (bf16)0.f;
        bf16x8 z = {z0, z0, z0, z0, z0, z0, z0, z0};
        *(bf16x8*)(outg + tid * 8) = z;
        return;
    }

    const int* ubase = udata + (size_t)g * USTRIDE;
    const int nu = ubase[0];
    if (tid < 64) {
        upat_l[tid] = (tid < nu) ? ubase[1 + tid] : 0;
        ucnt_l[tid] = (tid < nu) ? ubase[65 + tid] : 0;
    }
    wacc[w][lane] = 0.f; wacc[w][64 + lane] = 0.f; wacc[w][128 + lane] = 0.f;
    __syncthreads();

    const int fr = lane & 15;
    const int quad = lane >> 4;
    const float inv_n = 1.0f / (float)n;

    for (int c0 = 0; c0 < nu; c0 += 16) {
        {   // build 16 Q rows (bf16) in wave-private LDS
            const int ul = lane >> 2;
            const int j0 = (lane & 3) * 16;
            const bool valid = (c0 + ul) < nu;
            const int pat = upat_l[c0 + ul];
            const float* bpq = bq + h * 64 + j0;
            float4 q0 = *(const float4*)bpq;
            float4 q1 = *(const float4*)(bpq + 4);
            float4 q2 = *(const float4*)(bpq + 8);
            float4 q3 = *(const float4*)(bpq + 12);
            #pragma unroll
            for (int p = 0; p < 8; p++) {
                const int hp = (pat >> (3 * p)) & 7;
                const float* pp = P2 + (size_t)(hp * 8 + p) * D + h * 64 + j0;
                float4 t0 = *(const float4*)pp;
                float4 t1 = *(const float4*)(pp + 4);
                float4 t2 = *(const float4*)(pp + 8);
                float4 t3 = *(const float4*)(pp + 12);
                q0.x += t0.x; q0.y += t0.y; q0.z += t0.z; q0.w += t0.w;
                q1.x += t1.x; q1.y += t1.y; q1.z += t1.z; q1.w += t1.w;
                q2.x += t2.x; q2.y += t2.y; q2.z += t2.z; q2.w += t2.w;
                q3.x += t3.x; q3.y += t3.y; q3.z += t3.z; q3.w += t3.w;
            }
            if (!valid) {
                q0.x=q0.y=q0.z=q0.w=0.f; q1.x=q1.y=q1.z=q1.w=0.f;
                q2.x=q2.y=q2.z=q2.w=0.f; q3.x=q3.y=q3.z=q3.w=0.f;
            }
            bf16x8 b0 = {(bf16)q0.x,(bf16)q0.y,(bf16)q0.z,(bf16)q0.w,
                         (bf16)q1.x,(bf16)q1.y,(bf16)q1.z,(bf16)q1.w};
            bf16x8 b1 = {(bf16)q2.x,(bf16)q2.y,(bf16)q2.z,(bf16)q2.w,
                         (bf16)q3.x,(bf16)q3.y,(bf16)q3.z,(bf16)q3.w};
            *(bf16x8*)(&Qs[w][ul * 80 + j0])     = b0;
            *(bf16x8*)(&Qs[w][ul * 80 + j0 + 8]) = b1;
        }
        bf16x8 fa0 = *(const bf16x8*)(&Qs[w][fr * 80 + quad * 8]);
        bf16x8 fa1 = *(const bf16x8*)(&Qs[w][fr * 80 + 32 + quad * 8]);

        f32x4 sc[12];
        #pragma unroll
        for (int st = 0; st < 12; st++) {
            if (st * 16 < n) {
                int s = st * 16 + fr;
                int row = off + (s < n ? s : n - 1);
                const bf16* kp = Kb + (size_t)row * D + h * 64 + quad * 8;
                bf16x8 fb0 = *(const bf16x8*)kp;
                bf16x8 fb1 = *(const bf16x8*)(kp + 32);
                f32x4 a = {0.f, 0.f, 0.f, 0.f};
                a = __builtin_amdgcn_mfma_f32_16x16x32_bf16(fa0, fb0, a, 0, 0, 0);
                a = __builtin_amdgcn_mfma_f32_16x16x32_bf16(fa1, fb1, a, 0, 0, 0);
                if (s < n) {
                    sc[st].x = a.x * 0.125f; sc[st].y = a.y * 0.125f;
                    sc[st].z = a.z * 0.125f; sc[st].w = a.w * 0.125f;
                } else {
                    sc[st].x = sc[st].y = sc[st].z = sc[st].w = -1e30f;
                }
            } else {
                sc[st].x = sc[st].y = sc[st].z = sc[st].w = -1e30f;
            }
        }
        float m[4] = {-1e30f, -1e30f, -1e30f, -1e30f};
        #pragma unroll
        for (int st = 0; st < 12; st++) {
            m[0] = fmaxf(m[0], sc[st].x); m[1] = fmaxf(m[1], sc[st].y);
            m[2] = fmaxf(m[2], sc[st].z); m[3] = fmaxf(m[3], sc[st].w);
        }
        #pragma unroll
        for (int o = 1; o <= 8; o <<= 1) {
            #pragma unroll
            for (int r = 0; r < 4; r++) m[r] = fmaxf(m[r], __shfl_xor(m[r], o));
        }
        float den[4] = {0.f, 0.f, 0.f, 0.f};
        #pragma unroll
        for (int st = 0; st < 12; st++) {
            float e0 = __expf(sc[st].x - m[0]); float e1 = __expf(sc[st].y - m[1]);
            float e2 = __expf(sc[st].z - m[2]); float e3 = __expf(sc[st].w - m[3]);
            sc[st].x = e0; sc[st].y = e1; sc[st].z = e2; sc[st].w = e3;
            den[0] += e0; den[1] += e1; den[2] += e2; den[3] += e3;
        }
        #pragma unroll
        for (int o = 1; o <= 8; o <<= 1) {
            #pragma unroll
            for (int r = 0; r < 4; r++) den[r] += __shfl_xor(den[r], o);
        }
        float wf[4];
        #pragma unroll
        for (int r = 0; r < 4; r++)
            wf[r] = (float)ucnt_l[c0 + quad * 4 + r] * inv_n / den[r];
        #pragma unroll
        for (int st = 0; st < 12; st++) {
            float v = sc[st].x * wf[0] + sc[st].y * wf[1] + sc[st].z * wf[2] + sc[st].w * wf[3];
            v += __shfl_xor(v, 16);
            v += __shfl_xor(v, 32);
            if (lane < 16) wacc[w][st * 16 + lane] += v;
        }
    }

    // ---- fused abar: thread tid owns column tid for all 8 heads ----
    __syncthreads();
    const float* Ac = Af + (size_t)off * D + tid;
    float accv[8] = {};
    for (int s = 0; s < n; s++) {
        float av = Ac[(size_t)s * D];
        #pragma unroll
        for (int hh = 0; hh < 8; hh++) accv[hh] += wacc[hh][s] * av;
    }
    #pragma unroll
    for (int hh = 0; hh < 8; hh++) outg[hh * 512 + tid] = (bf16)accv[hh];
}

// ---------------- kernel: zero tmp ----------------
__global__ __launch_bounds__(256) void zero_kernel(float* __restrict__ p, int n4) {
    int i = blockIdx.x * 256 + threadIdx.x;
    if (i < n4) { float4 z = {0.f, 0.f, 0.f, 0.f}; *(float4*)(p + i * 4) = z; }
}

// ---------------- kernel: fused Wov GEMM, M=512 N=512 K=4096, split-K atomics ----------------
__global__ __launch_bounds__(256) void og_gemm(const bf16* __restrict__ Ab,
                                               const bf16* __restrict__ Bb,
                                               float* __restrict__ Yt) {
    const int o0 = blockIdx.x * 128;
    const int i0 = blockIdx.y * 128;
    const int k0 = blockIdx.z * 512;
    __shared__ bf16 As[128 * 32];
    __shared__ bf16 Bs[128 * 32];
    const int tid = threadIdx.x;
    const int lane = tid & 63;
    const int w = tid >> 6;
    const int wm = w & 1, wn = w >> 1;
    const int fr = lane & 15, quad = lane >> 4;
    const bf16* gA = Ab + (size_t)(i0 + w * 32 + (lane >> 2)) * 4096 + k0 + (lane & 3) * 8;
    const bf16* gB = Bb + (size_t)(o0 + w * 32 + (lane >> 2)) * 4096 + k0 + (lane & 3) * 8;
    bf16* lA = As + (w * 32) * 32;
    bf16* lB = Bs + (w * 32) * 32;

    f32x4 acc[4][4] = {};

    for (int kt = 0; kt < 512; kt += 32) {
        __syncthreads();
        gload_lds16(gA + kt, lA);
        gload_lds16(gA + (size_t)16 * 4096 + kt, lA + 16 * 32);
        gload_lds16(gB + kt, lB);
        gload_lds16(gB + (size_t)16 * 4096 + kt, lB + 16 * 32);
        __syncthreads();
        bf16x8 fa[4], fb[4];
        #pragma unroll
        for (int mf = 0; mf < 4; mf++)
            fa[mf] = *(const bf16x8*)(As + (wm * 64 + mf * 16 + fr) * 32 + quad * 8);
        #pragma unroll
        for (int nf = 0; nf < 4; nf++)
            fb[nf] = *(const bf16x8*)(Bs + (wn * 64 + nf * 16 + fr) * 32 + quad * 8);
        #pragma unroll
        for (int mf = 0; mf < 4; mf++)
            #pragma unroll
            for (int nf = 0; nf < 4; nf++)
                acc[mf][nf] = __builtin_amdgcn_mfma_f32_16x16x32_bf16(fa[mf], fb[nf], acc[mf][nf], 0, 0, 0);
    }
    #pragma unroll
    for (int nf = 0; nf < 4; nf++) {
        const int col = o0 + wn * 64 + nf * 16 + fr;
        #pragma unroll
        for (int mf = 0; mf < 4; mf++) {
            const int row = i0 + wm * 64 + mf * 16 + quad * 4;
            #pragma unroll
            for (int r = 0; r < 4; r++)
                atomicAdd(&Yt[(size_t)(row + r) * D + col], acc[mf][nf][r]);
        }
    }
}

// ---------------- kernel: final projection out = relu((tmp+cst|0) @ Wp^T + bp) ----------------
__global__ __launch_bounds__(256) void proj_p(const float* __restrict__ tmp,
                                              const float* __restrict__ cst,
                                              const bf16* __restrict__ Wpb,
                                              const float* __restrict__ bp,
                                              const int* __restrict__ lb,
                                              float* __restrict__ out) {
    const int o0 = blockIdx.x * 128;
    const int i0 = blockIdx.y * 128;
    __shared__ bf16 As[128 * 32];
    __shared__ bf16 Bs[128 * 32];
    const int tid = threadIdx.x;
    const int lane = tid & 63;
    const int w = tid >> 6;
    const int wm = w & 1, wn = w >> 1;
    const int fr = lane & 15, quad = lane >> 4;
    const int ar = tid >> 1;
    const int ac = (tid & 1) * 16;
    const int g = i0 + ar;
    const bool live = lb[g + 1] - lb[g] > 0;
    const float* tp = tmp + (size_t)g * D + ac;
    const float* cp = cst + ac;
    const bf16* gB = Wpb + (size_t)(o0 + w * 32 + (lane >> 2)) * D + (lane & 3) * 8;
    bf16* lB = Bs + (w * 32) * 32;

    f32x4 acc[4][4] = {};

    for (int kt = 0; kt < D; kt += 32) {
        __syncthreads();
        gload_lds16(gB + kt, lB);
        gload_lds16(gB + (size_t)16 * D + kt, lB + 16 * 32);
        {
            float4 x0 = *(const float4*)(tp + kt);
            float4 x1 = *(const float4*)(tp + kt + 4);
            float4 x2 = *(const float4*)(tp + kt + 8);
            float4 x3 = *(const float4*)(tp + kt + 12);
            float4 c0 = *(const float4*)(cp + kt);
            float4 c1 = *(const float4*)(cp + kt + 4);
            float4 c2 = *(const float4*)(cp + kt + 8);
            float4 c3 = *(const float4*)(cp + kt + 12);
            float s = live ? 1.f : 0.f;
            bf16x8 v0 = {(bf16)((x0.x+c0.x)*s),(bf16)((x0.y+c0.y)*s),(bf16)((x0.z+c0.z)*s),(bf16)((x0.w+c0.w)*s),
                         (bf16)((x1.x+c1.x)*s),(bf16)((x1.y+c1.y)*s),(bf16)((x1.z+c1.z)*s),(bf16)((x1.w+c1.w)*s)};
            bf16x8 v1 = {(bf16)((x2.x+c2.x)*s),(bf16)((x2.y+c2.y)*s),(bf16)((x2.z+c2.z)*s),(bf16)((x2.w+c2.w)*s),
                         (bf16)((x3.x+c3.x)*s),(bf16)((x3.y+c3.y)*s),(bf16)((x3.z+c3.z)*s),(bf16)((x3.w+c3.w)*s)};
            *(bf16x8*)(As + ar * 32 + ac) = v0;
            *(bf16x8*)(As + ar * 32 + ac + 8) = v1;
        }
        __syncthreads();
        bf16x8 fa[4], fb[4];
        #pragma unroll
        for (int mf = 0; mf < 4; mf++)
            fa[mf] = *(const bf16x8*)(As + (wm * 64 + mf * 16 + fr) * 32 + quad * 8);
        #pragma unroll
        for (int nf = 0; nf < 4; nf++)
            fb[nf] = *(const bf16x8*)(Bs + (wn * 64 + nf * 16 + fr) * 32 + quad * 8);
        #pragma unroll
        for (int mf = 0; mf < 4; mf++)
            #pragma unroll
            for (int nf = 0; nf < 4; nf++)
                acc[mf][nf] = __builtin_amdgcn_mfma_f32_16x16x32_bf16(fa[mf], fb[nf], acc[mf][nf], 0, 0, 0);
    }
    #pragma unroll
    for (int nf = 0; nf < 4; nf++) {
        const int col = o0 + wn * 64 + nf * 16 + fr;
        const float bs = bp[col];
        #pragma unroll
        for (int mf = 0; mf < 4; mf++) {
            const int row = i0 + wm * 64 + mf * 16 + quad * 4;
            #pragma unroll
            for (int r = 0; r < 4; r++)
                out[(size_t)(row + r) * D + col] = fmaxf(acc[mf][nf][r] + bs, 0.f);
        }
    }
}

extern "C" void kernel_launch(void* const* d_in, const int* in_sizes, int n_in,
                              void* d_out, int out_size, void* d_ws, size_t ws_size,
                              hipStream_t stream) {
    const float* nf    = (const float*)d_in[0];
    const int*   batch = (const int*)d_in[1];
    const float* gq    = (const float*)d_in[2];
    const float* wq    = (const float*)d_in[3];
    const float* bq    = (const float*)d_in[4];
    const float* wk    = (const float*)d_in[5];
    const float* bk    = (const float*)d_in[6];
    const float* wv    = (const float*)d_in[7];
    const float* bv    = (const float*)d_in[8];
    const float* wo    = (const float*)d_in[9];
    const float* bo    = (const float*)d_in[10];
    const float* wp    = (const float*)d_in[11];
    const float* bp    = (const float*)d_in[12];
    float* out = (float*)d_out;

    // workspace layout:
    // [2Mi,6Mi): abar | [6Mi,10Mi): Wov | [10Mi,11Mi): tmp | [11Mi,+4K): cst
    // [64Mi,128Mi): Kb.  [128Mi, ...): lb, udata, Wkb, Wpb, P2, perm.
    char* ws = (char*)d_ws;
    bf16*  abar = (bf16*)(ws + ((size_t)2 << 20));
    bf16*  Wov  = (bf16*)(ws + ((size_t)6 << 20));
    float* tmp  = (float*)(ws + ((size_t)10 << 20));
    float* cst  = (float*)(ws + ((size_t)11 << 20));
    bf16*  Kb   = (bf16*)(ws + ((size_t)64 << 20));
    char* sm = ws + ((size_t)128 << 20);
    int*  lb    = (int*)sm;    sm += 4096;
    int*  udata = (int*)sm;    sm += (size_t)NUM_GRAPHS * USTRIDE * 4 + 2048;
    bf16* Wkb   = (bf16*)sm;   sm += (size_t)D * D * 2;
    bf16* Wpb   = (bf16*)sm;   sm += (size_t)D * D * 2;
    float* P2   = (float*)sm;  sm += (size_t)64 * D * 4;
    int*  perm  = (int*)sm;    sm += NUM_GRAPHS * 4;

    lb_kernel<<<3, 256, 0, stream>>>(batch, lb);
    sortg_kernel<<<1, 512, 0, stream>>>(lb, perm);
    dedup_kernel<<<NUM_GRAPHS, 192, 0, stream>>>(lb, udata);
    cvt_kernel<<<(D * D / 4) / 256, 256, 0, stream>>>(wk, Wkb, D * D);
    cvt_kernel<<<(D * D / 4) / 256, 256, 0, stream>>>(wp, Wpb, D * D);
    p2_kernel<<<dim3(8, 8), 256, 0, stream>>>(gq, wq, P2);
    k_gemm<<<2048, 256, 0, stream>>>(nf, Wkb, bk, Kb);
    wov_kernel<<<dim3(16, 8), 256, 0, stream>>>(wo, wv, Wov);
    cst_kernel<<<2, 256, 0, stream>>>(wo, bv, bo, cst);
    attn_kernel<<<NUM_GRAPHS, 512, 0, stream>>>(Kb, P2, bq, lb, udata, nf, perm, abar);
    zero_kernel<<<(NUM_GRAPHS * D / 4 + 255) / 256, 256, 0, stream>>>(tmp, NUM_GRAPHS * D / 4);
    og_gemm<<<dim3(4, 4, 8), 256, 0, stream>>>(abar, Wov, tmp);
    proj_p<<<dim3(4, 4), 256, 0, stream>>>(tmp, cst, Wpb, bp, lb, out);
}

// Round 8
// 425.856 us; speedup vs baseline: 1.0557x; 1.0250x over previous
//
#include <hip/hip_runtime.h>
#include <hip/hip_bf16.h>
#include <cstdint>

typedef __bf16 bf16;
typedef __attribute__((ext_vector_type(8))) __bf16 bf16x8;
typedef __attribute__((ext_vector_type(4))) __bf16 bf16x4;
typedef __attribute__((ext_vector_type(2))) __bf16 bf16x2;
typedef __attribute__((ext_vector_type(4))) float f32x4;

#define N_NODES    65536
#define NUM_GRAPHS 512
#define MAX_N      192
#define D          512
#define H          8
#define DH         64
#define UMAX       64
#define USTRIDE    132

__device__ __forceinline__ void gload_lds16(const void* g, void* l) {
    __builtin_amdgcn_global_load_lds((const __attribute__((address_space(1))) void*)g,
                                     (__attribute__((address_space(3))) void*)l, 16, 0, 0);
}

// ---------------- kernel: graph boundaries ----------------
__global__ __launch_bounds__(256) void lb_kernel(const int* __restrict__ batch,
                                                 int* __restrict__ lb) {
    int g = blockIdx.x * 256 + threadIdx.x;
    if (g > NUM_GRAPHS) return;
    int lo = 0, hi = N_NODES;
    while (lo < hi) {
        int mid = (lo + hi) >> 1;
        if (batch[mid] < g) lo = mid + 1; else hi = mid;
    }
    lb[g] = lo;
}

// ---------------- kernel: descending-n permutation (load balance for attn) ----
__global__ __launch_bounds__(512) void sortg_kernel(const int* __restrict__ lb,
                                                    int* __restrict__ perm) {
    __shared__ int hist[MAX_N + 1];
    __shared__ int base[MAX_N + 1];
    const int t = threadIdx.x;
    if (t <= MAX_N) hist[t] = 0;
    __syncthreads();
    const int n = min(lb[t + 1] - lb[t], MAX_N);
    atomicAdd(&hist[n], 1);
    __syncthreads();
    if (t == 0) {
        int acc = 0;
        for (int k = MAX_N; k >= 0; k--) { base[k] = acc; acc += hist[k]; }
    }
    __syncthreads();
    int pos = atomicAdd(&base[n], 1);
    perm[pos] = t;
}

// ---------------- kernel: per-graph unique Q-row patterns ----------------
__global__ __launch_bounds__(192) void dedup_kernel(const int* __restrict__ lb,
                                                    int* __restrict__ udata) {
    const int g = blockIdx.x;
    const int off = lb[g];
    const int n = min(lb[g + 1] - off, MAX_N);
    __shared__ int keys[MAX_N];
    __shared__ int ukey[UMAX], ucnt[UMAX];
    __shared__ int nu_s;
    const int t = threadIdx.x;
    if (t < n) {
        unsigned un = (unsigned)n;
        int key = 0;
        #pragma unroll
        for (int p = 0; p < 8; p++) key |= (int)(((unsigned)(8 * t + p)) / un) << (3 * p);
        keys[t] = key;
    }
    __syncthreads();
    if (t == 0) {
        int nu = 0;
        for (int s = 0; s < n; s++) {
            if (s == 0 || keys[s] != keys[s - 1]) {
                if (nu < UMAX) { ukey[nu] = keys[s]; ucnt[nu] = 0; nu++; }
            }
            ucnt[nu - 1] += 1;
        }
        nu_s = nu;
    }
    __syncthreads();
    const int nu = nu_s;
    int* base = udata + (size_t)g * USTRIDE;
    if (t == 0) base[0] = nu;
    if (t < nu) { base[1 + t] = ukey[t]; base[65 + t] = ucnt[t]; }
}

// ---------------- kernel: fp32 -> bf16 convert (weights only) ----------------
__global__ __launch_bounds__(256) void cvt_kernel(const float* __restrict__ src,
                                                  bf16* __restrict__ dst, int n) {
    int i = (blockIdx.x * 256 + threadIdx.x) * 4;
    if (i >= n) return;
    float4 v = *(const float4*)(src + i);
    bf16x4 o = {(bf16)v.x, (bf16)v.y, (bf16)v.z, (bf16)v.w};
    *(bf16x4*)(dst + i) = o;
}

// ---------------- kernel: P2[h][p][o] = sum_j gq[h*64+j]*wq[o,64p+j] ----------------
__global__ __launch_bounds__(256) void p2_kernel(const float* __restrict__ gq,
                                                 const float* __restrict__ wq,
                                                 float* __restrict__ P2) {
    int h = blockIdx.x, p = blockIdx.y;
    __shared__ float gs[64];
    if (threadIdx.x < 64) gs[threadIdx.x] = gq[h * 64 + threadIdx.x];
    __syncthreads();
    for (int o = threadIdx.x; o < D; o += 256) {
        const float* wr = wq + (size_t)o * D + p * 64;
        float acc = 0.f;
        #pragma unroll 16
        for (int j = 0; j < 64; j++) acc += gs[j] * wr[j];
        P2[(size_t)(h * 8 + p) * D + o] = acc;
    }
}

// ---------------- kernel: Wov[o, h*512+d'] = sum_j wo[o,h*64+j]*wv[h*64+j,d'] ----------------
__global__ __launch_bounds__(256) void wov_kernel(const float* __restrict__ wo,
                                                  const float* __restrict__ wv,
                                                  bf16* __restrict__ Wov) {
    const int ot = blockIdx.x;   // o block of 32
    const int h  = blockIdx.y;
    __shared__ float wos[32 * 64];
    for (int idx = threadIdx.x; idx < 32 * 64; idx += 256) {
        int ol = idx >> 6, j = idx & 63;
        wos[idx] = wo[(size_t)(ot * 32 + ol) * D + h * 64 + j];
    }
    __syncthreads();
    const int c = threadIdx.x * 2;
    float acc0[32] = {}, acc1[32] = {};
    for (int j = 0; j < 64; j++) {
        float2 v2 = *(const float2*)(wv + (size_t)(h * 64 + j) * D + c);
        #pragma unroll
        for (int o = 0; o < 32; o++) {
            float wj = wos[o * 64 + j];
            acc0[o] += wj * v2.x; acc1[o] += wj * v2.y;
        }
    }
    #pragma unroll
    for (int o = 0; o < 32; o++) {
        bf16x2 r = {(bf16)acc0[o], (bf16)acc1[o]};
        *(bf16x2*)(Wov + (size_t)(ot * 32 + o) * 4096 + h * 512 + c) = r;
    }
}

// ---------------- kernel: cst[o] = wo[o,:].bv + bo[o] ----------------
__global__ __launch_bounds__(256) void cst_kernel(const float* __restrict__ wo,
                                                  const float* __restrict__ bv,
                                                  const float* __restrict__ bo,
                                                  float* __restrict__ cst) {
    int o = blockIdx.x * 256 + threadIdx.x;
    if (o >= D) return;
    const float* wr = wo + (size_t)o * D;
    float acc = bo[o];
    for (int d0 = 0; d0 < D; d0 += 4) {
        float4 wv4 = *(const float4*)(wr + d0);
        float4 b4  = *(const float4*)(bv + d0);
        acc += wv4.x * b4.x + wv4.y * b4.y + wv4.z * b4.z + wv4.w * b4.w;
    }
    cst[o] = acc;
}

// ---------------- kernel: K GEMM, 128x128 tile, fp32-A direct, 2-phase dbuf ----
// T3 minimum 2-phase pipeline, safe form: STAGE tile t+1 into the other LDS
// buffer BEFORE computing tile t; then one __syncthreads() per phase (hipcc
// lowers it to s_waitcnt vmcnt(0) lgkmcnt(0) + s_barrier -- the drain lands
// AFTER the MFMA cluster, so staging latency hides under compute).  No inline
// asm (rule #18: hipcc can reorder around asm waitcnts; R7's raw-barrier
// variant may have hung the container).  Race check: compute(buf) reads are
// lgkm-drained before each wave's barrier; barrier orders all waves; only
// then is buf re-staged.  fp32-A source-swizzle (c16^=row&7) + same XOR on
// the read keeps A-fragment ds_reads conflict-free.  XCD grid swizzle +
// LDS-staged epilogue kept.
__global__ __launch_bounds__(256) void k_gemm(const float* __restrict__ Af,
                                              const bf16* __restrict__ Wkb,
                                              const float* __restrict__ bkb,
                                              bf16* __restrict__ Kout) {
    const int lin = blockIdx.x;          // 0..2047
    const int xcd = lin & 7;
    const int idx = lin >> 3;            // 0..255
    const int nt  = idx & 3;             // n-tile fast within XCD
    const int ml  = idx >> 2;            // 0..63
    const int i0 = (xcd * 64 + ml) * 128;
    const int o0 = nt * 128;

    __shared__ char smem[49152];
    // buf0: Asf0[128][32]f32 @0 (16K) | Bs0[128][32]bf16 @16384 (8K)
    // buf1: Asf1 @24576 | Bs1 @40960
    float* Asf0 = (float*)smem;
    bf16*  Bs0  = (bf16*)(smem + 16384);
    float* Asf1 = (float*)(smem + 24576);
    bf16*  Bs1  = (bf16*)(smem + 40960);

    const int tid = threadIdx.x;
    const int lane = tid & 63;
    const int w = tid >> 6;
    const int wm = w & 1, wn = w >> 1;
    const int fr = lane & 15, quad = lane >> 4;

    // A staging: lane covers row (lane>>3) of an 8-row slab, 16B col unit (lane&7),
    // source col XOR-swizzled by row&7.
    const int sra = lane >> 3;                     // 0..7
    const int c16 = lane & 7;
    const int scol = ((c16 ^ sra) << 2);           // floats
    const float* gA = Af + (size_t)(i0 + w * 32 + sra) * D + scol;
    float* lA0 = Asf0 + (w * 32) * 32;
    float* lA1 = Asf1 + (w * 32) * 32;

    // B staging (bf16, linear)
    const bf16* gB = Wkb + (size_t)(o0 + w * 32 + (lane >> 2)) * D + (lane & 3) * 8;
    bf16* lB0 = Bs0 + (w * 32) * 32;
    bf16* lB1 = Bs1 + (w * 32) * 32;

    f32x4 acc[4][4] = {};

#define KSTAGE(AB, BB, KT) do {                                              \
        gload_lds16(gA + (KT), (AB));                                        \
        gload_lds16(gA + (size_t)8  * D + (KT), (AB) + 8  * 32);             \
        gload_lds16(gA + (size_t)16 * D + (KT), (AB) + 16 * 32);             \
        gload_lds16(gA + (size_t)24 * D + (KT), (AB) + 24 * 32);             \
        gload_lds16(gB + (KT), (BB));                                        \
        gload_lds16(gB + (size_t)16 * D + (KT), (BB) + 16 * 32);             \
    } while (0)

#define KCOMPUTE(ASF, BS) do {                                               \
        bf16x8 fa[4], fb[4];                                                 \
        _Pragma("unroll")                                                    \
        for (int mf = 0; mf < 4; mf++) {                                     \
            const int row = wm * 64 + mf * 16 + fr;                          \
            const int u0 = (quad * 2) ^ (row & 7);                           \
            const int u1 = (quad * 2 + 1) ^ (row & 7);                       \
            f32x4 a0 = *(const f32x4*)((ASF) + row * 32 + u0 * 4);           \
            f32x4 a1 = *(const f32x4*)((ASF) + row * 32 + u1 * 4);           \
            bf16x8 v = {(bf16)a0.x,(bf16)a0.y,(bf16)a0.z,(bf16)a0.w,         \
                        (bf16)a1.x,(bf16)a1.y,(bf16)a1.z,(bf16)a1.w};        \
            fa[mf] = v;                                                      \
        }                                                                    \
        _Pragma("unroll")                                                    \
        for (int nf = 0; nf < 4; nf++)                                       \
            fb[nf] = *(const bf16x8*)((BS) + (wn * 64 + nf * 16 + fr) * 32 + quad * 8); \
        _Pragma("unroll")                                                    \
        for (int mf = 0; mf < 4; mf++)                                       \
            _Pragma("unroll")                                                \
            for (int nf = 0; nf < 4; nf++)                                   \
                acc[mf][nf] = __builtin_amdgcn_mfma_f32_16x16x32_bf16(fa[mf], fb[nf], acc[mf][nf], 0, 0, 0); \
    } while (0)

    // prologue: stage tile 0 into buf0
    KSTAGE(lA0, lB0, 0);
    __syncthreads();

    for (int kt = 0; kt < D; kt += 64) {
        // phase A: stage kt+32 -> buf1 (issue first), compute kt from buf0
        KSTAGE(lA1, lB1, kt + 32);
        KCOMPUTE(Asf0, Bs0);
        __syncthreads();                 // drain lands after compute
        // phase B: stage kt+64 -> buf0 (unless done), compute kt+32 from buf1
        if (kt + 64 < D) KSTAGE(lA0, lB0, kt + 64);
        KCOMPUTE(Asf1, Bs1);
        __syncthreads();
    }
#undef KSTAGE
#undef KCOMPUTE

    // epilogue: stage each 64-row half in LDS (stride 132 -> conflict-free),
    // then coalesced bf16x8 stores.
    bf16* Cs = (bf16*)smem;
    #pragma unroll
    for (int pass = 0; pass < 2; pass++) {
        __syncthreads();
        if (wm == pass) {
            #pragma unroll
            for (int nf = 0; nf < 4; nf++) {
                const int col = wn * 64 + nf * 16 + fr;
                const float bs = bkb[o0 + col];
                #pragma unroll
                for (int mf = 0; mf < 4; mf++) {
                    #pragma unroll
                    for (int r = 0; r < 4; r++)
                        Cs[(mf * 16 + quad * 4 + r) * 132 + col] = (bf16)(acc[mf][nf][r] + bs);
                }
            }
        }
        __syncthreads();
        #pragma unroll
        for (int k = 0; k < 4; k++) {
            int idx2 = k * 256 + tid;            // 0..1023
            int row = idx2 >> 4;                 // 0..63
            int coff = (idx2 & 15) * 8;          // 0..120
            bf16x8 v = *(const bf16x8*)(Cs + row * 132 + coff);
            *(bf16x8*)(Kout + (size_t)(i0 + pass * 64 + row) * D + o0 + coff) = v;
        }
    }
}

// ---------------- kernel: attention + fused abar ----------------
// grid NUM_GRAPHS blocks x 512 threads; block processes graph perm[blockIdx]
// (descending-n order -> longest-first scheduling trims the makespan tail).
// wave w == head h.  K read inside the c0 loop (L1/L2-served).  abar phase:
// thread tid owns output column tid for all 8 heads.
__global__ __launch_bounds__(512) void attn_kernel(const bf16* __restrict__ Kb,
                                                   const float* __restrict__ P2,
                                                   const float* __restrict__ bq,
                                                   const int* __restrict__ lb,
                                                   const int* __restrict__ udata,
                                                   const float* __restrict__ Af,
                                                   const int* __restrict__ perm,
                                                   bf16* __restrict__ abar) {
    const int g = perm[blockIdx.x];
    const int tid = threadIdx.x;
    const int lane = tid & 63;
    const int w = tid >> 6;          // 0..7 == head
    const int h = w;
    const int off = lb[g];
    const int n = min(lb[g + 1] - off, MAX_N);

    __shared__ bf16 Qs[8][16 * 80];
    __shared__ float wacc[8][MAX_N];
    __shared__ int upat_l[UMAX], ucnt_l[UMAX];

    bf16* outg = abar + (size_t)g * 4096;
    if (n == 0) {
        const bf16 z0 = (bf16)0.f;
        bf16x8 z = {z0, z0, z0, z0, z0, z0, z0, z0};
        *(bf16x8*)(outg + tid * 8) = z;
        return;
    }

    const int* ubase = udata + (size_t)g * USTRIDE;
    const int nu = ubase[0];
    if (tid < 64) {
        upat_l[tid] = (tid < nu) ? ubase[1 + tid] : 0;
        ucnt_l[tid] = (tid < nu) ? ubase[65 + tid] : 0;
    }
    wacc[w][lane] = 0.f; wacc[w][64 + lane] = 0.f; wacc[w][128 + lane] = 0.f;
    __syncthreads();

    const int fr = lane & 15;
    const int quad = lane >> 4;
    const float inv_n = 1.0f / (float)n;

    for (int c0 = 0; c0 < nu; c0 += 16) {
        {   // build 16 Q rows (bf16) in wave-private LDS
            const int ul = lane >> 2;
            const int j0 = (lane & 3) * 16;
            const bool valid = (c0 + ul) < nu;
            const int pat = upat_l[c0 + ul];
            const float* bpq = bq + h * 64 + j0;
            float4 q0 = *(const float4*)bpq;
            float4 q1 = *(const float4*)(bpq + 4);
            float4 q2 = *(const float4*)(bpq + 8);
            float4 q3 = *(const float4*)(bpq + 12);
            #pragma unroll
            for (int p = 0; p < 8; p++) {
                const int hp = (pat >> (3 * p)) & 7;
                const float* pp = P2 + (size_t)(hp * 8 + p) * D + h * 64 + j0;
                float4 t0 = *(const float4*)pp;
                float4 t1 = *(const float4*)(pp + 4);
                float4 t2 = *(const float4*)(pp + 8);
                float4 t3 = *(const float4*)(pp + 12);
                q0.x += t0.x; q0.y += t0.y; q0.z += t0.z; q0.w += t0.w;
                q1.x += t1.x; q1.y += t1.y; q1.z += t1.z; q1.w += t1.w;
                q2.x += t2.x; q2.y += t2.y; q2.z += t2.z; q2.w += t2.w;
                q3.x += t3.x; q3.y += t3.y; q3.z += t3.z; q3.w += t3.w;
            }
            if (!valid) {
                q0.x=q0.y=q0.z=q0.w=0.f; q1.x=q1.y=q1.z=q1.w=0.f;
                q2.x=q2.y=q2.z=q2.w=0.f; q3.x=q3.y=q3.z=q3.w=0.f;
            }
            bf16x8 b0 = {(bf16)q0.x,(bf16)q0.y,(bf16)q0.z,(bf16)q0.w,
                         (bf16)q1.x,(bf16)q1.y,(bf16)q1.z,(bf16)q1.w};
            bf16x8 b1 = {(bf16)q2.x,(bf16)q2.y,(bf16)q2.z,(bf16)q2.w,
                         (bf16)q3.x,(bf16)q3.y,(bf16)q3.z,(bf16)q3.w};
            *(bf16x8*)(&Qs[w][ul * 80 + j0])     = b0;
            *(bf16x8*)(&Qs[w][ul * 80 + j0 + 8]) = b1;
        }
        bf16x8 fa0 = *(const bf16x8*)(&Qs[w][fr * 80 + quad * 8]);
        bf16x8 fa1 = *(const bf16x8*)(&Qs[w][fr * 80 + 32 + quad * 8]);

        f32x4 sc[12];
        #pragma unroll
        for (int st = 0; st < 12; st++) {
            if (st * 16 < n) {
                int s = st * 16 + fr;
                int row = off + (s < n ? s : n - 1);
                const bf16* kp = Kb + (size_t)row * D + h * 64 + quad * 8;
                bf16x8 fb0 = *(const bf16x8*)kp;
                bf16x8 fb1 = *(const bf16x8*)(kp + 32);
                f32x4 a = {0.f, 0.f, 0.f, 0.f};
                a = __builtin_amdgcn_mfma_f32_16x16x32_bf16(fa0, fb0, a, 0, 0, 0);
                a = __builtin_amdgcn_mfma_f32_16x16x32_bf16(fa1, fb1, a, 0, 0, 0);
                if (s < n) {
                    sc[st].x = a.x * 0.125f; sc[st].y = a.y * 0.125f;
                    sc[st].z = a.z * 0.125f; sc[st].w = a.w * 0.125f;
                } else {
                    sc[st].x = sc[st].y = sc[st].z = sc[st].w = -1e30f;
                }
            } else {
                sc[st].x = sc[st].y = sc[st].z = sc[st].w = -1e30f;
            }
        }
        float m[4] = {-1e30f, -1e30f, -1e30f, -1e30f};
        #pragma unroll
        for (int st = 0; st < 12; st++) {
            m[0] = fmaxf(m[0], sc[st].x); m[1] = fmaxf(m[1], sc[st].y);
            m[2] = fmaxf(m[2], sc[st].z); m[3] = fmaxf(m[3], sc[st].w);
        }
        #pragma unroll
        for (int o = 1; o <= 8; o <<= 1) {
            #pragma unroll
            for (int r = 0; r < 4; r++) m[r] = fmaxf(m[r], __shfl_xor(m[r], o));
        }
        float den[4] = {0.f, 0.f, 0.f, 0.f};
        #pragma unroll
        for (int st = 0; st < 12; st++) {
            float e0 = __expf(sc[st].x - m[0]); float e1 = __expf(sc[st].y - m[1]);
            float e2 = __expf(sc[st].z - m[2]); float e3 = __expf(sc[st].w - m[3]);
            sc[st].x = e0; sc[st].y = e1; sc[st].z = e2; sc[st].w = e3;
            den[0] += e0; den[1] += e1; den[2] += e2; den[3] += e3;
        }
        #pragma unroll
        for (int o = 1; o <= 8; o <<= 1) {
            #pragma unroll
            for (int r = 0; r < 4; r++) den[r] += __shfl_xor(den[r], o);
        }
        float wf[4];
        #pragma unroll
        for (int r = 0; r < 4; r++)
            wf[r] = (float)ucnt_l[c0 + quad * 4 + r] * inv_n / den[r];
        #pragma unroll
        for (int st = 0; st < 12; st++) {
            float v = sc[st].x * wf[0] + sc[st].y * wf[1] + sc[st].z * wf[2] + sc[st].w * wf[3];
            v += __shfl_xor(v, 16);
            v += __shfl_xor(v, 32);
            if (lane < 16) wacc[w][st * 16 + lane] += v;
        }
    }

    // ---- fused abar: thread tid owns column tid for all 8 heads ----
    __syncthreads();
    const float* Ac = Af + (size_t)off * D + tid;
    float accv[8] = {};
    for (int s = 0; s < n; s++) {
        float av = Ac[(size_t)s * D];
        #pragma unroll
        for (int hh = 0; hh < 8; hh++) accv[hh] += wacc[hh][s] * av;
    }
    #pragma unroll
    for (int hh = 0; hh < 8; hh++) outg[hh * 512 + tid] = (bf16)accv[hh];
}

// ---------------- kernel: zero tmp ----------------
__global__ __launch_bounds__(256) void zero_kernel(float* __restrict__ p, int n4) {
    int i = blockIdx.x * 256 + threadIdx.x;
    if (i < n4) { float4 z = {0.f, 0.f, 0.f, 0.f}; *(float4*)(p + i * 4) = z; }
}

// ---------------- kernel: fused Wov GEMM, M=512 N=512 K=4096, split-K atomics ----------------
__global__ __launch_bounds__(256) void og_gemm(const bf16* __restrict__ Ab,
                                               const bf16* __restrict__ Bb,
                                               float* __restrict__ Yt) {
    const int o0 = blockIdx.x * 128;
    const int i0 = blockIdx.y * 128;
    const int k0 = blockIdx.z * 512;
    __shared__ bf16 As[128 * 32];
    __shared__ bf16 Bs[128 * 32];
    const int tid = threadIdx.x;
    const int lane = tid & 63;
    const int w = tid >> 6;
    const int wm = w & 1, wn = w >> 1;
    const int fr = lane & 15, quad = lane >> 4;
    const bf16* gA = Ab + (size_t)(i0 + w * 32 + (lane >> 2)) * 4096 + k0 + (lane & 3) * 8;
    const bf16* gB = Bb + (size_t)(o0 + w * 32 + (lane >> 2)) * 4096 + k0 + (lane & 3) * 8;
    bf16* lA = As + (w * 32) * 32;
    bf16* lB = Bs + (w * 32) * 32;

    f32x4 acc[4][4] = {};

    for (int kt = 0; kt < 512; kt += 32) {
        __syncthreads();
        gload_lds16(gA + kt, lA);
        gload_lds16(gA + (size_t)16 * 4096 + kt, lA + 16 * 32);
        gload_lds16(gB + kt, lB);
        gload_lds16(gB + (size_t)16 * 4096 + kt, lB + 16 * 32);
        __syncthreads();
        bf16x8 fa[4], fb[4];
        #pragma unroll
        for (int mf = 0; mf < 4; mf++)
            fa[mf] = *(const bf16x8*)(As + (wm * 64 + mf * 16 + fr) * 32 + quad * 8);
        #pragma unroll
        for (int nf = 0; nf < 4; nf++)
            fb[nf] = *(const bf16x8*)(Bs + (wn * 64 + nf * 16 + fr) * 32 + quad * 8);
        #pragma unroll
        for (int mf = 0; mf < 4; mf++)
            #pragma unroll
            for (int nf = 0; nf < 4; nf++)
                acc[mf][nf] = __builtin_amdgcn_mfma_f32_16x16x32_bf16(fa[mf], fb[nf], acc[mf][nf], 0, 0, 0);
    }
    #pragma unroll
    for (int nf = 0; nf < 4; nf++) {
        const int col = o0 + wn * 64 + nf * 16 + fr;
        #pragma unroll
        for (int mf = 0; mf < 4; mf++) {
            const int row = i0 + wm * 64 + mf * 16 + quad * 4;
            #pragma unroll
            for (int r = 0; r < 4; r++)
                atomicAdd(&Yt[(size_t)(row + r) * D + col], acc[mf][nf][r]);
        }
    }
}

// ---------------- kernel: final projection out = relu((tmp+cst|0) @ Wp^T + bp) ----------------
__global__ __launch_bounds__(256) void proj_p(const float* __restrict__ tmp,
                                              const float* __restrict__ cst,
                                              const bf16* __restrict__ Wpb,
                                              const float* __restrict__ bp,
                                              const int* __restrict__ lb,
                                              float* __restrict__ out) {
    const int o0 = blockIdx.x * 128;
    const int i0 = blockIdx.y * 128;
    __shared__ bf16 As[128 * 32];
    __shared__ bf16 Bs[128 * 32];
    const int tid = threadIdx.x;
    const int lane = tid & 63;
    const int w = tid >> 6;
    const int wm = w & 1, wn = w >> 1;
    const int fr = lane & 15, quad = lane >> 4;
    const int ar = tid >> 1;
    const int ac = (tid & 1) * 16;
    const int g = i0 + ar;
    const bool live = lb[g + 1] - lb[g] > 0;
    const float* tp = tmp + (size_t)g * D + ac;
    const float* cp = cst + ac;
    const bf16* gB = Wpb + (size_t)(o0 + w * 32 + (lane >> 2)) * D + (lane & 3) * 8;
    bf16* lB = Bs + (w * 32) * 32;

    f32x4 acc[4][4] = {};

    for (int kt = 0; kt < D; kt += 32) {
        __syncthreads();
        gload_lds16(gB + kt, lB);
        gload_lds16(gB + (size_t)16 * D + kt, lB + 16 * 32);
        {
            float4 x0 = *(const float4*)(tp + kt);
            float4 x1 = *(const float4*)(tp + kt + 4);
            float4 x2 = *(const float4*)(tp + kt + 8);
            float4 x3 = *(const float4*)(tp + kt + 12);
            float4 c0 = *(const float4*)(cp + kt);
            float4 c1 = *(const float4*)(cp + kt + 4);
            float4 c2 = *(const float4*)(cp + kt + 8);
            float4 c3 = *(const float4*)(cp + kt + 12);
            float s = live ? 1.f : 0.f;
            bf16x8 v0 = {(bf16)((x0.x+c0.x)*s),(bf16)((x0.y+c0.y)*s),(bf16)((x0.z+c0.z)*s),(bf16)((x0.w+c0.w)*s),
                         (bf16)((x1.x+c1.x)*s),(bf16)((x1.y+c1.y)*s),(bf16)((x1.z+c1.z)*s),(bf16)((x1.w+c1.w)*s)};
            bf16x8 v1 = {(bf16)((x2.x+c2.x)*s),(bf16)((x2.y+c2.y)*s),(bf16)((x2.z+c2.z)*s),(bf16)((x2.w+c2.w)*s),
                         (bf16)((x3.x+c3.x)*s),(bf16)((x3.y+c3.y)*s),(bf16)((x3.z+c3.z)*s),(bf16)((x3.w+c3.w)*s)};
            *(bf16x8*)(As + ar * 32 + ac) = v0;
            *(bf16x8*)(As + ar * 32 + ac + 8) = v1;
        }
        __syncthreads();
        bf16x8 fa[4], fb[4];
        #pragma unroll
        for (int mf = 0; mf < 4; mf++)
            fa[mf] = *(const bf16x8*)(As + (wm * 64 + mf * 16 + fr) * 32 + quad * 8);
        #pragma unroll
        for (int nf = 0; nf < 4; nf++)
            fb[nf] = *(const bf16x8*)(Bs + (wn * 64 + nf * 16 + fr) * 32 + quad * 8);
        #pragma unroll
        for (int mf = 0; mf < 4; mf++)
            #pragma unroll
            for (int nf = 0; nf < 4; nf++)
                acc[mf][nf] = __builtin_amdgcn_mfma_f32_16x16x32_bf16(fa[mf], fb[nf], acc[mf][nf], 0, 0, 0);
    }
    #pragma unroll
    for (int nf = 0; nf < 4; nf++) {
        const int col = o0 + wn * 64 + nf * 16 + fr;
        const float bs = bp[col];
        #pragma unroll
        for (int mf = 0; mf < 4; mf++) {
            const int row = i0 + wm * 64 + mf * 16 + quad * 4;
            #pragma unroll
            for (int r = 0; r < 4; r++)
                out[(size_t)(row + r) * D + col] = fmaxf(acc[mf][nf][r] + bs, 0.f);
        }
    }
}

extern "C" void kernel_launch(void* const* d_in, const int* in_sizes, int n_in,
                              void* d_out, int out_size, void* d_ws, size_t ws_size,
                              hipStream_t stream) {
    const float* nf    = (const float*)d_in[0];
    const int*   batch = (const int*)d_in[1];
    const float* gq    = (const float*)d_in[2];
    const float* wq    = (const float*)d_in[3];
    const float* bq    = (const float*)d_in[4];
    const float* wk    = (const float*)d_in[5];
    const float* bk    = (const float*)d_in[6];
    const float* wv    = (const float*)d_in[7];
    const float* bv    = (const float*)d_in[8];
    const float* wo    = (const float*)d_in[9];
    const float* bo    = (const float*)d_in[10];
    const float* wp    = (const float*)d_in[11];
    const float* bp    = (const float*)d_in[12];
    float* out = (float*)d_out;

    // workspace layout:
    // [2Mi,6Mi): abar | [6Mi,10Mi): Wov | [10Mi,11Mi): tmp | [11Mi,+4K): cst
    // [64Mi,128Mi): Kb.  [128Mi, ...): lb, udata, Wkb, Wpb, P2, perm.
    char* ws = (char*)d_ws;
    bf16*  abar = (bf16*)(ws + ((size_t)2 << 20));
    bf16*  Wov  = (bf16*)(ws + ((size_t)6 << 20));
    float* tmp  = (float*)(ws + ((size_t)10 << 20));
    float* cst  = (float*)(ws + ((size_t)11 << 20));
    bf16*  Kb   = (bf16*)(ws + ((size_t)64 << 20));
    char* sm = ws + ((size_t)128 << 20);
    int*  lb    = (int*)sm;    sm += 4096;
    int*  udata = (int*)sm;    sm += (size_t)NUM_GRAPHS * USTRIDE * 4 + 2048;
    bf16* Wkb   = (bf16*)sm;   sm += (size_t)D * D * 2;
    bf16* Wpb   = (bf16*)sm;   sm += (size_t)D * D * 2;
    float* P2   = (float*)sm;  sm += (size_t)64 * D * 4;
    int*  perm  = (int*)sm;    sm += NUM_GRAPHS * 4;

    lb_kernel<<<3, 256, 0, stream>>>(batch, lb);
    sortg_kernel<<<1, 512, 0, stream>>>(lb, perm);
    dedup_kernel<<<NUM_GRAPHS, 192, 0, stream>>>(lb, udata);
    cvt_kernel<<<(D * D / 4) / 256, 256, 0, stream>>>(wk, Wkb, D * D);
    cvt_kernel<<<(D * D / 4) / 256, 256, 0, stream>>>(wp, Wpb, D * D);
    p2_kernel<<<dim3(8, 8), 256, 0, stream>>>(gq, wq, P2);
    k_gemm<<<2048, 256, 0, stream>>>(nf, Wkb, bk, Kb);
    wov_kernel<<<dim3(16, 8), 256, 0, stream>>>(wo, wv, Wov);
    cst_kernel<<<2, 256, 0, stream>>>(wo, bv, bo, cst);
    attn_kernel<<<NUM_GRAPHS, 512, 0, stream>>>(Kb, P2, bq, lb, udata, nf, perm, abar);
    zero_kernel<<<(NUM_GRAPHS * D / 4 + 255) / 256, 256, 0, stream>>>(tmp, NUM_GRAPHS * D / 4);
    og_gemm<<<dim3(4, 4, 8), 256, 0, stream>>>(abar, Wov, tmp);
    proj_p<<<dim3(4, 4), 256, 0, stream>>>(tmp, cst, Wpb, bp, lb, out);
}